// Round 1
// baseline (7190.909 us; speedup 1.0000x reference)
//
#include <hip/hip_runtime.h>
#include <hip/hip_bf16.h>

#define N_NODES 100000
#define N_EDGES 1600000
#define D_FEAT 256
#define HIDDEN 256
#define N_CLASSES 64

// ---------------- degree / dinv ----------------
__global__ __launch_bounds__(256) void init_deg(float* deg, int n) {
    int i = blockIdx.x * 256 + threadIdx.x;
    if (i < n) deg[i] = 1.0f;  // self loop
}

__global__ __launch_bounds__(256) void count_deg(const int* __restrict__ cols, float* deg, int nE) {
    int e = blockIdx.x * 256 + threadIdx.x;
    if (e < nE) atomicAdd(&deg[cols[e]], 1.0f);
}

__global__ __launch_bounds__(256) void finalize_dinv(float* deg, int n) {
    int i = blockIdx.x * 256 + threadIdx.x;
    if (i < n) deg[i] = rsqrtf(deg[i]);  // deg >= 1 always
}

// ---------------- GEMM: C0 = C1 = (A @ B) * rowscale ----------------
#define BM 64
#define BN 64
#define BK 32

__global__ __launch_bounds__(256)
void gemm_dual(const float* __restrict__ A, const float* __restrict__ B,
               const float* __restrict__ rowscale,   // may be nullptr
               float* __restrict__ C0, float* __restrict__ C1,
               int M, int N, int K)
{
    __shared__ __align__(16) float As[BK][BM + 4];
    __shared__ __align__(16) float Bs[BK][BN + 4];
    int tid = threadIdx.x;
    int bx = blockIdx.x;   // along N
    int by = blockIdx.y;   // along M
    int row0 = by * BM, col0 = bx * BN;
    int tx = tid & 15, ty = tid >> 4;

    float acc[4][4] = {};

    for (int k0 = 0; k0 < K; k0 += BK) {
        // A tile: 64 rows x 32 cols = 512 float4, 2 per thread; store transposed
        #pragma unroll
        for (int l = 0; l < 2; ++l) {
            int idx = tid + l * 256;          // 0..511
            int r = idx >> 3;                 // row in tile (8 float4 per row)
            int cc = (idx & 7) << 2;          // col in tile
            int grow = row0 + r;
            float4 v = make_float4(0.f, 0.f, 0.f, 0.f);
            if (grow < M) v = *(const float4*)&A[(long)grow * K + k0 + cc];
            As[cc + 0][r] = v.x; As[cc + 1][r] = v.y;
            As[cc + 2][r] = v.z; As[cc + 3][r] = v.w;
        }
        // B tile: 32 rows x 64 cols = 512 float4, 2 per thread
        #pragma unroll
        for (int l = 0; l < 2; ++l) {
            int idx = tid + l * 256;
            int r = idx >> 4;                 // 16 float4 per row
            int cc = (idx & 15) << 2;
            float4 v = *(const float4*)&B[(long)(k0 + r) * N + col0 + cc];
            *(float4*)&Bs[r][cc] = v;
        }
        __syncthreads();

        #pragma unroll
        for (int kk = 0; kk < BK; ++kk) {
            float4 a4 = *(const float4*)&As[kk][ty << 2];
            float4 b4 = *(const float4*)&Bs[kk][tx << 2];
            float a[4] = {a4.x, a4.y, a4.z, a4.w};
            float b[4] = {b4.x, b4.y, b4.z, b4.w};
            #pragma unroll
            for (int i = 0; i < 4; ++i)
                #pragma unroll
                for (int j = 0; j < 4; ++j)
                    acc[i][j] = fmaf(a[i], b[j], acc[i][j]);
        }
        __syncthreads();
    }

    #pragma unroll
    for (int i = 0; i < 4; ++i) {
        int grow = row0 + (ty << 2) + i;
        if (grow >= M) break;
        float s = rowscale ? rowscale[grow] : 1.0f;
        #pragma unroll
        for (int j = 0; j < 4; ++j) {
            float v = acc[i][j] * s;
            long off = (long)grow * N + col0 + (tx << 2) + j;
            C0[off] = v;
            C1[off] = v;
        }
    }
}

// ---------------- edge scatter: acc[col] += src[row] ----------------
__global__ __launch_bounds__(256)
void scatter_f4(const int* __restrict__ rows, const int* __restrict__ cols,
                const float* __restrict__ src, float* __restrict__ acc,
                int nEdges, int f4shift, int F)
{
    int t = blockIdx.x * 256 + threadIdx.x;
    int e = t >> f4shift;
    if (e >= nEdges) return;
    int f4 = t & ((1 << f4shift) - 1);
    int r = rows[e], c = cols[e];
    float4 v = *(const float4*)&src[(long)r * F + (f4 << 2)];
    float* dst = &acc[(long)c * F + (f4 << 2)];
    atomicAdd(dst + 0, v.x);
    atomicAdd(dst + 1, v.y);
    atomicAdd(dst + 2, v.z);
    atomicAdd(dst + 3, v.w);
}

// ---------------- epilogue 1: r1s = dinv * relu(dinv*acc + b1) ----------------
__global__ __launch_bounds__(256)
void epilogue1(const float* __restrict__ acc1, const float* __restrict__ dinv,
               const float* __restrict__ b1, float* __restrict__ r1s, int total4)
{
    int i = blockIdx.x * 256 + threadIdx.x;
    if (i >= total4) return;
    int c = i >> 6;            // HIDDEN/4 = 64 float4 per node
    int f4 = i & 63;
    float d = dinv[c];
    float4 a = ((const float4*)acc1)[i];
    float4 bb = *(const float4*)&b1[f4 << 2];
    float4 o;
    o.x = d * fmaxf(fmaf(d, a.x, bb.x), 0.f);
    o.y = d * fmaxf(fmaf(d, a.y, bb.y), 0.f);
    o.z = d * fmaxf(fmaf(d, a.z, bb.z), 0.f);
    o.w = d * fmaxf(fmaf(d, a.w, bb.w), 0.f);
    ((float4*)r1s)[i] = o;
}

// ---------------- epilogue 2: out = dinv*acc2 + b2 (in place on d_out) -----
__global__ __launch_bounds__(256)
void epilogue2(float* __restrict__ out, const float* __restrict__ dinv,
               const float* __restrict__ b2, int total4)
{
    int i = blockIdx.x * 256 + threadIdx.x;
    if (i >= total4) return;
    int c = i >> 4;            // N_CLASSES/4 = 16 float4 per node
    int f4 = i & 15;
    float d = dinv[c];
    float4 a = ((float4*)out)[i];
    float4 bb = *(const float4*)&b2[f4 << 2];
    float4 o;
    o.x = fmaf(d, a.x, bb.x);
    o.y = fmaf(d, a.y, bb.y);
    o.z = fmaf(d, a.z, bb.z);
    o.w = fmaf(d, a.w, bb.w);
    ((float4*)out)[i] = o;
}

extern "C" void kernel_launch(void* const* d_in, const int* in_sizes, int n_in,
                              void* d_out, int out_size, void* d_ws, size_t ws_size,
                              hipStream_t stream)
{
    const float* x  = (const float*)d_in[0];
    const int*   ei = (const int*)d_in[1];
    const float* W1 = (const float*)d_in[2];
    const float* b1 = (const float*)d_in[3];
    const float* W2 = (const float*)d_in[4];
    const float* b2 = (const float*)d_in[5];
    float* out = (float*)d_out;

    const int* rows = ei;            // edge_index[0] = source
    const int* cols = ei + N_EDGES;  // edge_index[1] = target

    char* ws = (char*)d_ws;
    float* dinv = (float*)ws;                                  // 400 KB
    float* hs1  = (float*)(ws + (1 << 19));                    // 102.4 MB
    float* acc1 = (float*)(ws + (1 << 19) + 102400000);        // 102.4 MB (reused as hs2)
    float* hs2  = acc1;

    // degree -> dinv
    init_deg<<<(N_NODES + 255) / 256, 256, 0, stream>>>(dinv, N_NODES);
    count_deg<<<(N_EDGES + 255) / 256, 256, 0, stream>>>(cols, dinv, N_EDGES);
    finalize_dinv<<<(N_NODES + 255) / 256, 256, 0, stream>>>(dinv, N_NODES);

    // GEMM1: hs1 = (x @ W1) * dinv[row]; acc1 initialized = hs1 (self-loop)
    {
        dim3 grid(HIDDEN / BN, (N_NODES + BM - 1) / BM);
        gemm_dual<<<grid, 256, 0, stream>>>(x, W1, dinv, hs1, acc1,
                                            N_NODES, HIDDEN, D_FEAT);
    }

    // scatter 1: acc1[col] += hs1[row]   (256 feats, f4shift=6)
    {
        long work = (long)N_EDGES * (HIDDEN / 4);
        scatter_f4<<<(int)((work + 255) / 256), 256, 0, stream>>>(
            rows, cols, hs1, acc1, N_EDGES, 6, HIDDEN);
    }

    // epilogue 1: r1s (into hs1 buffer) = dinv * relu(dinv*acc1 + b1)
    {
        int total4 = N_NODES * HIDDEN / 4;
        epilogue1<<<(total4 + 255) / 256, 256, 0, stream>>>(acc1, dinv, b1, hs1, total4);
    }

    // GEMM2: hs2 = r1s @ W2 (dinv-row-scale already folded); d_out init = hs2
    {
        dim3 grid(N_CLASSES / BN, (N_NODES + BM - 1) / BM);
        gemm_dual<<<grid, 256, 0, stream>>>(hs1, W2, nullptr, hs2, out,
                                            N_NODES, N_CLASSES, HIDDEN);
    }

    // scatter 2: out[col] += hs2[row]   (64 feats, f4shift=4)
    {
        long work = (long)N_EDGES * (N_CLASSES / 4);
        scatter_f4<<<(int)((work + 255) / 256), 256, 0, stream>>>(
            rows, cols, hs2, out, N_EDGES, 4, N_CLASSES);
    }

    // epilogue 2: out = dinv*out + b2
    {
        int total4 = N_NODES * N_CLASSES / 4;
        epilogue2<<<(total4 + 255) / 256, 256, 0, stream>>>(out, dinv, b2, total4);
    }
}

// Round 2
// 923.032 us; speedup vs baseline: 7.7905x; 7.7905x over previous
//
#include <hip/hip_runtime.h>
#include <hip/hip_bf16.h>

#define N_NODES 100000
#define N_EDGES 1600000
#define D_FEAT 256
#define HIDDEN 256
#define N_CLASSES 64

#define SCAN_NBLK 98   // ceil(100000/1024)

// ---------------- degree counting ----------------
__global__ __launch_bounds__(256) void init_work(int* work, int n) {
    int i = blockIdx.x * 256 + threadIdx.x;
    if (i < n) work[i] = 0;
}

__global__ __launch_bounds__(256) void count_deg(const int* __restrict__ cols, int* work, int nE) {
    int e = blockIdx.x * 256 + threadIdx.x;
    if (e < nE) atomicAdd(&work[cols[e]], 1);
}

// ---------------- scan (exclusive prefix sum over degrees) ----------------
__global__ __launch_bounds__(256)
void scan_blocks(const int* __restrict__ work, int* __restrict__ bsum) {
    __shared__ int sd[256];
    int b = blockIdx.x, t = threadIdx.x;
    int base = b * 1024 + t * 4;
    int s = 0;
    #pragma unroll
    for (int j = 0; j < 4; ++j) {
        int i = base + j;
        if (i < N_NODES) s += work[i];
    }
    sd[t] = s; __syncthreads();
    for (int off = 128; off > 0; off >>= 1) {
        if (t < off) sd[t] += sd[t + off];
        __syncthreads();
    }
    if (t == 0) bsum[b] = sd[0];
}

__global__ __launch_bounds__(128)
void scan_top(int* __restrict__ bsum, int* __restrict__ offsets) {
    __shared__ int sd[128];
    int t = threadIdx.x;
    sd[t] = (t < SCAN_NBLK) ? bsum[t] : 0;
    __syncthreads();
    #pragma unroll
    for (int off = 1; off < 128; off <<= 1) {
        int v = (t >= off) ? sd[t - off] : 0;
        __syncthreads();
        sd[t] += v;
        __syncthreads();
    }
    int excl = (t > 0) ? sd[t - 1] : 0;
    if (t < SCAN_NBLK) bsum[t] = excl;
    if (t == 0) offsets[N_NODES] = N_EDGES;
}

// writes offsets[i] (exclusive), resets work[i] to cursor start, computes dinv
__global__ __launch_bounds__(256)
void scan_down(int* __restrict__ work, const int* __restrict__ bsum,
               int* __restrict__ offsets, float* __restrict__ dinv) {
    __shared__ int sd[256];
    int b = blockIdx.x, t = threadIdx.x;
    int base = b * 1024 + t * 4;
    int d[4];
    int tsum = 0;
    #pragma unroll
    for (int j = 0; j < 4; ++j) {
        int i = base + j;
        d[j] = (i < N_NODES) ? work[i] : 0;
        tsum += d[j];
    }
    sd[t] = tsum; __syncthreads();
    #pragma unroll
    for (int off = 1; off < 256; off <<= 1) {
        int v = (t >= off) ? sd[t - off] : 0;
        __syncthreads();
        sd[t] += v;
        __syncthreads();
    }
    int run = bsum[b] + sd[t] - tsum;   // exclusive prefix for this thread
    #pragma unroll
    for (int j = 0; j < 4; ++j) {
        int i = base + j;
        if (i < N_NODES) {
            offsets[i] = run;
            work[i] = run;                       // cursor
            dinv[i] = rsqrtf(1.0f + (float)d[j]); // deg incl self loop
            run += d[j];
        }
    }
}

// ---------------- CSR fill: edge_src sorted by target ----------------
__global__ __launch_bounds__(256)
void fill_csr(const int* __restrict__ rows, const int* __restrict__ cols,
              int* work, int* __restrict__ esrc, int nE) {
    int e = blockIdx.x * 256 + threadIdx.x;
    if (e >= nE) return;
    int p = atomicAdd(&work[cols[e]], 1);
    esrc[p] = rows[e];
}

// ---------------- GEMM: C[M x 64] = (A[M x K] @ B[K x 64]) * rowscale ------
#define BM 64
#define BK 32

__global__ __launch_bounds__(256)
void gemm_rs(const float* __restrict__ A, int K,
             const float* __restrict__ B, int ldb,
             const float* __restrict__ rowscale,   // nullable
             float* __restrict__ C, int M)
{
    __shared__ __align__(16) float As[BK][BM + 4];
    __shared__ __align__(16) float Bs[BK][64 + 4];
    int tid = threadIdx.x;
    int row0 = blockIdx.x * BM;
    int tx = tid & 15, ty = tid >> 4;

    float acc[4][4] = {};

    for (int k0 = 0; k0 < K; k0 += BK) {
        #pragma unroll
        for (int l = 0; l < 2; ++l) {
            int idx = tid + l * 256;          // 0..511
            int r = idx >> 3;                 // 8 float4 per row of 32
            int cc = (idx & 7) << 2;
            int grow = row0 + r;
            float4 v = make_float4(0.f, 0.f, 0.f, 0.f);
            if (grow < M) v = *(const float4*)&A[(long)grow * K + k0 + cc];
            As[cc + 0][r] = v.x; As[cc + 1][r] = v.y;
            As[cc + 2][r] = v.z; As[cc + 3][r] = v.w;
        }
        #pragma unroll
        for (int l = 0; l < 2; ++l) {
            int idx = tid + l * 256;
            int r = idx >> 4;                 // 16 float4 per row of 64
            int cc = (idx & 15) << 2;
            float4 v = *(const float4*)&B[(long)(k0 + r) * ldb + cc];
            *(float4*)&Bs[r][cc] = v;
        }
        __syncthreads();

        #pragma unroll
        for (int kk = 0; kk < BK; ++kk) {
            float4 a4 = *(const float4*)&As[kk][ty << 2];
            float4 b4 = *(const float4*)&Bs[kk][tx << 2];
            float a[4] = {a4.x, a4.y, a4.z, a4.w};
            float b[4] = {b4.x, b4.y, b4.z, b4.w};
            #pragma unroll
            for (int i = 0; i < 4; ++i)
                #pragma unroll
                for (int j = 0; j < 4; ++j)
                    acc[i][j] = fmaf(a[i], b[j], acc[i][j]);
        }
        __syncthreads();
    }

    #pragma unroll
    for (int i = 0; i < 4; ++i) {
        int grow = row0 + (ty << 2) + i;
        if (grow >= M) break;
        float s = rowscale ? rowscale[grow] : 1.0f;
        float4 o = make_float4(acc[i][0] * s, acc[i][1] * s, acc[i][2] * s, acc[i][3] * s);
        *(float4*)&C[(long)grow * 64 + (tx << 2)] = o;
    }
}

// ---------------- CSR aggregate: one wave per node, 64 feats ----------------
// out[v] = dinv[v]*(src[v] + sum_e src[esrc[e]]) + bias  (then optional relu*dinv)
template<bool RELU_FOLD>
__global__ __launch_bounds__(256)
void aggregate(const float* __restrict__ src,        // [N, 64]
               const int* __restrict__ offsets, const int* __restrict__ esrc,
               const float* __restrict__ dinv, const float* __restrict__ bias,
               float* __restrict__ out, int out_ld)
{
    int wave = threadIdx.x >> 6, lane = threadIdx.x & 63;
    int v = blockIdx.x * 4 + wave;
    float acc = src[(long)v * 64 + lane];  // self loop term
    int e = offsets[v], end = offsets[v + 1];
    for (; e + 4 <= end; e += 4) {
        int s0 = esrc[e], s1 = esrc[e + 1], s2 = esrc[e + 2], s3 = esrc[e + 3];
        float a0 = src[(long)s0 * 64 + lane];
        float a1 = src[(long)s1 * 64 + lane];
        float a2 = src[(long)s2 * 64 + lane];
        float a3 = src[(long)s3 * 64 + lane];
        acc += (a0 + a1) + (a2 + a3);
    }
    for (; e < end; ++e) acc += src[(long)esrc[e] * 64 + lane];
    float dv = dinv[v];
    float r = fmaf(dv, acc, bias[lane]);
    if (RELU_FOLD) r = dv * fmaxf(r, 0.0f);
    out[(long)v * out_ld + lane] = r;
}

// ---------------- workspace layout (bytes) ----------------
#define WS_DINV   0UL
#define WS_OFFS   524288UL      // (N+1) ints
#define WS_WORK   1048576UL     // N ints (deg, then cursor)
#define WS_BSUM   1572864UL     // 98 ints
#define WS_ESRC   2097152UL     // N_EDGES ints
#define WS_CHUNK  8912896UL     // 100k x 64 f32 = 25.6 MB
#define WS_R1S    35651584UL    // 100k x 256 f32 = 102.4 MB

extern "C" void kernel_launch(void* const* d_in, const int* in_sizes, int n_in,
                              void* d_out, int out_size, void* d_ws, size_t ws_size,
                              hipStream_t stream)
{
    const float* x  = (const float*)d_in[0];
    const int*   ei = (const int*)d_in[1];
    const float* W1 = (const float*)d_in[2];
    const float* b1 = (const float*)d_in[3];
    const float* W2 = (const float*)d_in[4];
    const float* b2 = (const float*)d_in[5];
    float* out = (float*)d_out;

    const int* rows = ei;            // sources
    const int* cols = ei + N_EDGES;  // targets

    char* ws = (char*)d_ws;
    float* dinv    = (float*)(ws + WS_DINV);
    int*   offsets = (int*)(ws + WS_OFFS);
    int*   work    = (int*)(ws + WS_WORK);
    int*   bsum    = (int*)(ws + WS_BSUM);
    int*   esrc    = (int*)(ws + WS_ESRC);
    float* chunk   = (float*)(ws + WS_CHUNK);
    float* r1s     = (float*)(ws + WS_R1S);

    // --- CSR build ---
    init_work<<<(N_NODES + 255) / 256, 256, 0, stream>>>(work, N_NODES);
    count_deg<<<(N_EDGES + 255) / 256, 256, 0, stream>>>(cols, work, N_EDGES);
    scan_blocks<<<SCAN_NBLK, 256, 0, stream>>>(work, bsum);
    scan_top<<<1, 128, 0, stream>>>(bsum, offsets);
    scan_down<<<SCAN_NBLK, 256, 0, stream>>>(work, bsum, offsets, dinv);
    fill_csr<<<(N_EDGES + 255) / 256, 256, 0, stream>>>(rows, cols, work, esrc, N_EDGES);

    const int gemm_grid = (N_NODES + BM - 1) / BM;
    const int agg_grid  = N_NODES / 4;

    // --- layer 1, chunked over 4 x 64 output features ---
    for (int fc = 0; fc < 4; ++fc) {
        // chunk = (x @ W1[:, fc*64:+64]) * dinv[row]
        gemm_rs<<<gemm_grid, 256, 0, stream>>>(x, D_FEAT, W1 + fc * 64, HIDDEN,
                                               dinv, chunk, N_NODES);
        // r1s[:, fc*64:+64] = dinv * relu(dinv * agg(chunk) + b1[fc])
        aggregate<true><<<agg_grid, 256, 0, stream>>>(chunk, offsets, esrc, dinv,
                                                      b1 + fc * 64,
                                                      r1s + fc * 64, HIDDEN);
    }

    // --- layer 2 ---
    gemm_rs<<<gemm_grid, 256, 0, stream>>>(r1s, HIDDEN, W2, N_CLASSES,
                                           nullptr, chunk, N_NODES);
    aggregate<false><<<agg_grid, 256, 0, stream>>>(chunk, offsets, esrc, dinv,
                                                   b2, out, N_CLASSES);
}

// Round 3
// 902.317 us; speedup vs baseline: 7.9694x; 1.0230x over previous
//
#include <hip/hip_runtime.h>
#include <hip/hip_bf16.h>

#define N_NODES 100000
#define N_EDGES 1600000
#define D_FEAT 256
#define HIDDEN 256
#define N_CLASSES 64

#define SCAN_NBLK 98   // ceil(100000/1024)

// ---------------- degree counting ----------------
__global__ __launch_bounds__(256) void init_work(int* work, int n) {
    int i = blockIdx.x * 256 + threadIdx.x;
    if (i < n) work[i] = 0;
}

__global__ __launch_bounds__(256) void count_deg(const int* __restrict__ cols, int* work, int nE) {
    int e = blockIdx.x * 256 + threadIdx.x;
    if (e < nE) atomicAdd(&work[cols[e]], 1);
}

// ---------------- scan (exclusive prefix sum over degrees) ----------------
__global__ __launch_bounds__(256)
void scan_blocks(const int* __restrict__ work, int* __restrict__ bsum) {
    __shared__ int sd[256];
    int b = blockIdx.x, t = threadIdx.x;
    int base = b * 1024 + t * 4;
    int s = 0;
    #pragma unroll
    for (int j = 0; j < 4; ++j) {
        int i = base + j;
        if (i < N_NODES) s += work[i];
    }
    sd[t] = s; __syncthreads();
    for (int off = 128; off > 0; off >>= 1) {
        if (t < off) sd[t] += sd[t + off];
        __syncthreads();
    }
    if (t == 0) bsum[b] = sd[0];
}

__global__ __launch_bounds__(128)
void scan_top(int* __restrict__ bsum, int* __restrict__ offsets) {
    __shared__ int sd[128];
    int t = threadIdx.x;
    sd[t] = (t < SCAN_NBLK) ? bsum[t] : 0;
    __syncthreads();
    #pragma unroll
    for (int off = 1; off < 128; off <<= 1) {
        int v = (t >= off) ? sd[t - off] : 0;
        __syncthreads();
        sd[t] += v;
        __syncthreads();
    }
    int excl = (t > 0) ? sd[t - 1] : 0;
    if (t < SCAN_NBLK) bsum[t] = excl;
    if (t == 0) offsets[N_NODES] = N_EDGES;
}

__global__ __launch_bounds__(256)
void scan_down(int* __restrict__ work, const int* __restrict__ bsum,
               int* __restrict__ offsets, float* __restrict__ dinv) {
    __shared__ int sd[256];
    int b = blockIdx.x, t = threadIdx.x;
    int base = b * 1024 + t * 4;
    int d[4];
    int tsum = 0;
    #pragma unroll
    for (int j = 0; j < 4; ++j) {
        int i = base + j;
        d[j] = (i < N_NODES) ? work[i] : 0;
        tsum += d[j];
    }
    sd[t] = tsum; __syncthreads();
    #pragma unroll
    for (int off = 1; off < 256; off <<= 1) {
        int v = (t >= off) ? sd[t - off] : 0;
        __syncthreads();
        sd[t] += v;
        __syncthreads();
    }
    int run = bsum[b] + sd[t] - tsum;
    #pragma unroll
    for (int j = 0; j < 4; ++j) {
        int i = base + j;
        if (i < N_NODES) {
            offsets[i] = run;
            work[i] = run;                        // cursor
            dinv[i] = rsqrtf(1.0f + (float)d[j]); // deg incl self loop
            run += d[j];
        }
    }
}

// ---------------- CSR fill: edge sources sorted by target ----------------
__global__ __launch_bounds__(256)
void fill_csr(const int* __restrict__ rows, const int* __restrict__ cols,
              int* work, int* __restrict__ esrc, int nE) {
    int e = blockIdx.x * 256 + threadIdx.x;
    if (e >= nE) return;
    int p = atomicAdd(&work[cols[e]], 1);
    esrc[p] = rows[e];
}

// ---------------- GEMM: C = (A @ B) * rowscale ----------------
// Tile BM=64*QM x BN=64*QN, 256 threads, per-thread (4*QM)x(4*QN) accum.
template<int QM, int QN>
__global__ __launch_bounds__(256)
void gemm_tile(const float* __restrict__ A, int K,
               const float* __restrict__ B, int ldb,
               const float* __restrict__ rowscale,   // nullable
               float* __restrict__ C, int ldc, int M)
{
    constexpr int BM = 64 * QM, BN = 64 * QN;
    __shared__ __align__(16) float As[32][BM + 4];
    __shared__ __align__(16) float Bs[32][BN + 4];
    int tid = threadIdx.x;
    int row0 = blockIdx.y * BM, col0 = blockIdx.x * BN;
    int tx = tid & 15, ty = tid >> 4;

    float acc[QM][QN][4][4] = {};

    for (int k0 = 0; k0 < K; k0 += 32) {
        // A tile: BM x 32, store transposed As[k][m]
        #pragma unroll
        for (int l = 0; l < BM / 32; ++l) {
            int idx = tid + l * 256;
            int r = idx >> 3, cc = (idx & 7) << 2;
            int grow = row0 + r;
            float4 v = make_float4(0.f, 0.f, 0.f, 0.f);
            if (grow < M) v = *(const float4*)&A[(long)grow * K + k0 + cc];
            As[cc + 0][r] = v.x; As[cc + 1][r] = v.y;
            As[cc + 2][r] = v.z; As[cc + 3][r] = v.w;
        }
        // B tile: 32 x BN
        #pragma unroll
        for (int l = 0; l < BN / 32; ++l) {
            int idx = tid + l * 256;
            constexpr int BN4 = BN / 4;
            int r = idx / BN4, cc = (idx % BN4) << 2;
            *(float4*)&Bs[r][cc] = *(const float4*)&B[(long)(k0 + r) * ldb + col0 + cc];
        }
        __syncthreads();

        #pragma unroll 8
        for (int kk = 0; kk < 32; ++kk) {
            float a[QM][4], b[QN][4];
            #pragma unroll
            for (int qm = 0; qm < QM; ++qm) {
                float4 t = *(const float4*)&As[kk][qm * 64 + (ty << 2)];
                a[qm][0] = t.x; a[qm][1] = t.y; a[qm][2] = t.z; a[qm][3] = t.w;
            }
            #pragma unroll
            for (int qn = 0; qn < QN; ++qn) {
                float4 t = *(const float4*)&Bs[kk][qn * 64 + (tx << 2)];
                b[qn][0] = t.x; b[qn][1] = t.y; b[qn][2] = t.z; b[qn][3] = t.w;
            }
            #pragma unroll
            for (int qm = 0; qm < QM; ++qm)
                #pragma unroll
                for (int qn = 0; qn < QN; ++qn)
                    #pragma unroll
                    for (int i = 0; i < 4; ++i)
                        #pragma unroll
                        for (int j = 0; j < 4; ++j)
                            acc[qm][qn][i][j] = fmaf(a[qm][i], b[qn][j], acc[qm][qn][i][j]);
        }
        __syncthreads();
    }

    #pragma unroll
    for (int qm = 0; qm < QM; ++qm)
        #pragma unroll
        for (int i = 0; i < 4; ++i) {
            int grow = row0 + qm * 64 + (ty << 2) + i;
            if (grow >= M) continue;
            float s = rowscale ? rowscale[grow] : 1.0f;
            #pragma unroll
            for (int qn = 0; qn < QN; ++qn) {
                float4 o = make_float4(acc[qm][qn][i][0] * s, acc[qm][qn][i][1] * s,
                                       acc[qm][qn][i][2] * s, acc[qm][qn][i][3] * s);
                *(float4*)&C[(long)grow * ldc + col0 + qn * 64 + (tx << 2)] = o;
            }
        }
}

// ---------------- CSR aggregate, 128 feats (float2/lane), wave per node -----
// out[v] = dinv*(src[v] + sum src[esrc]) + bias; optional relu then *dinv fold
template<bool RELU_FOLD>
__global__ __launch_bounds__(256)
void aggregate128(const float* __restrict__ src,        // [N, 128]
                  const int* __restrict__ offsets, const int* __restrict__ esrc,
                  const float* __restrict__ dinv, const float* __restrict__ bias,
                  float* __restrict__ out, int out_ld)
{
    int wave = threadIdx.x >> 6, lane = threadIdx.x & 63;
    int v = blockIdx.x * 4 + wave;
    int c = lane << 1;
    float2 sv = *(const float2*)&src[(long)v * 128 + c];
    float ax = sv.x, ay = sv.y;
    int e = offsets[v], end = offsets[v + 1];
    for (; e + 4 <= end; e += 4) {
        int s0 = esrc[e], s1 = esrc[e + 1], s2 = esrc[e + 2], s3 = esrc[e + 3];
        float2 a0 = *(const float2*)&src[(long)s0 * 128 + c];
        float2 a1 = *(const float2*)&src[(long)s1 * 128 + c];
        float2 a2 = *(const float2*)&src[(long)s2 * 128 + c];
        float2 a3 = *(const float2*)&src[(long)s3 * 128 + c];
        ax += (a0.x + a1.x) + (a2.x + a3.x);
        ay += (a0.y + a1.y) + (a2.y + a3.y);
    }
    for (; e < end; ++e) {
        float2 t = *(const float2*)&src[(long)esrc[e] * 128 + c];
        ax += t.x; ay += t.y;
    }
    float dv = dinv[v];
    float2 bb = *(const float2*)&bias[c];
    float rx = fmaf(dv, ax, bb.x), ry = fmaf(dv, ay, bb.y);
    if (RELU_FOLD) { rx = dv * fmaxf(rx, 0.f); ry = dv * fmaxf(ry, 0.f); }
    *(float2*)&out[(long)v * out_ld + c] = make_float2(rx, ry);
}

// ---------------- CSR aggregate, 64 feats (float/lane), wave per node -------
__global__ __launch_bounds__(256)
void aggregate64(const float* __restrict__ src,          // [N, 64]
                 const int* __restrict__ offsets, const int* __restrict__ esrc,
                 const float* __restrict__ dinv, const float* __restrict__ bias,
                 float* __restrict__ out)
{
    int wave = threadIdx.x >> 6, lane = threadIdx.x & 63;
    int v = blockIdx.x * 4 + wave;
    float acc = src[(long)v * 64 + lane];
    int e = offsets[v], end = offsets[v + 1];
    for (; e + 4 <= end; e += 4) {
        int s0 = esrc[e], s1 = esrc[e + 1], s2 = esrc[e + 2], s3 = esrc[e + 3];
        float a0 = src[(long)s0 * 64 + lane];
        float a1 = src[(long)s1 * 64 + lane];
        float a2 = src[(long)s2 * 64 + lane];
        float a3 = src[(long)s3 * 64 + lane];
        acc += (a0 + a1) + (a2 + a3);
    }
    for (; e < end; ++e) acc += src[(long)esrc[e] * 64 + lane];
    float dv = dinv[v];
    out[(long)v * 64 + lane] = fmaf(dv, acc, bias[lane]);
}

// ---------------- workspace layout (bytes) ----------------
#define WS_DINV   0UL
#define WS_OFFS   524288UL
#define WS_WORK   1048576UL
#define WS_BSUM   1572864UL
#define WS_ESRC   2097152UL      // 6.4 MB
#define WS_HSA    8912896UL      // 100k x 128 f32 = 51.2 MB
#define WS_R1S    60112896UL     // 100k x 256 f32 = 102.4 MB
#define WS_H2     162512896UL    // 100k x 64 f32 = 25.6 MB  (ends ~188.1 MB)

extern "C" void kernel_launch(void* const* d_in, const int* in_sizes, int n_in,
                              void* d_out, int out_size, void* d_ws, size_t ws_size,
                              hipStream_t stream)
{
    const float* x  = (const float*)d_in[0];
    const int*   ei = (const int*)d_in[1];
    const float* W1 = (const float*)d_in[2];
    const float* b1 = (const float*)d_in[3];
    const float* W2 = (const float*)d_in[4];
    const float* b2 = (const float*)d_in[5];
    float* out = (float*)d_out;

    const int* rows = ei;            // sources
    const int* cols = ei + N_EDGES;  // targets

    char* ws = (char*)d_ws;
    float* dinv    = (float*)(ws + WS_DINV);
    int*   offsets = (int*)(ws + WS_OFFS);
    int*   work    = (int*)(ws + WS_WORK);
    int*   bsum    = (int*)(ws + WS_BSUM);
    int*   esrc    = (int*)(ws + WS_ESRC);
    float* hsA     = (float*)(ws + WS_HSA);
    float* r1s     = (float*)(ws + WS_R1S);
    float* h2      = (float*)(ws + WS_H2);

    // --- CSR build ---
    init_work<<<(N_NODES + 255) / 256, 256, 0, stream>>>(work, N_NODES);
    count_deg<<<(N_EDGES + 255) / 256, 256, 0, stream>>>(cols, work, N_EDGES);
    scan_blocks<<<SCAN_NBLK, 256, 0, stream>>>(work, bsum);
    scan_top<<<1, 128, 0, stream>>>(bsum, offsets);
    scan_down<<<SCAN_NBLK, 256, 0, stream>>>(work, bsum, offsets, dinv);
    fill_csr<<<(N_EDGES + 255) / 256, 256, 0, stream>>>(rows, cols, work, esrc, N_EDGES);

    const int agg_grid = N_NODES / 4;

    // --- layer 1: two 128-feature chunks ---
    for (int fc = 0; fc < 2; ++fc) {
        // hsA = (x @ W1[:, fc*128 : +128]) * dinv[row]
        dim3 g1(1, (N_NODES + 127) / 128);
        gemm_tile<2, 2><<<g1, 256, 0, stream>>>(x, D_FEAT, W1 + fc * 128, HIDDEN,
                                                dinv, hsA, 128, N_NODES);
        // r1s[:, fc*128:+128] = dinv * relu(dinv * agg(hsA) + b1[chunk])
        aggregate128<true><<<agg_grid, 256, 0, stream>>>(
            hsA, offsets, esrc, dinv, b1 + fc * 128, r1s + fc * 128, HIDDEN);
    }

    // --- layer 2 ---
    {
        dim3 g2(1, (N_NODES + 255) / 256);
        gemm_tile<4, 1><<<g2, 256, 0, stream>>>(r1s, HIDDEN, W2, N_CLASSES,
                                                nullptr, h2, 64, N_NODES);
        aggregate64<<<agg_grid, 256, 0, stream>>>(h2, offsets, esrc, dinv, b2, out);
    }
}

// Round 4
// 670.794 us; speedup vs baseline: 10.7200x; 1.3451x over previous
//
#include <hip/hip_runtime.h>
#include <hip/hip_bf16.h>

#define N_NODES 100000
#define N_PAD   100032          // padded rows for MFMA tiles (64-row blocks)
#define N_EDGES 1600000
#define D_FEAT 256
#define HIDDEN 256
#define N_CLASSES 64

#define SCAN_NBLK 98   // ceil(100000/1024)

typedef __attribute__((ext_vector_type(8))) short bf16x8;
typedef __attribute__((ext_vector_type(4))) float f32x4;

__device__ inline float b2f(ushort u) {
    unsigned v = ((unsigned)u) << 16;
    float f; __builtin_memcpy(&f, &v, 4); return f;
}
__device__ inline ushort f2b(float f) {   // RNE
    unsigned u; __builtin_memcpy(&u, &f, 4);
    unsigned r = (u + 0x7fffu + ((u >> 16) & 1u)) >> 16;
    return (ushort)r;
}

// ---------------- degree counting ----------------
__global__ __launch_bounds__(256) void init_work(int* work, int n) {
    int i = blockIdx.x * 256 + threadIdx.x;
    if (i < n) work[i] = 0;
}

__global__ __launch_bounds__(256) void count_deg(const int* __restrict__ cols, int* work, int nE) {
    int e = blockIdx.x * 256 + threadIdx.x;
    if (e < nE) atomicAdd(&work[cols[e]], 1);
}

// ---------------- scan ----------------
__global__ __launch_bounds__(256)
void scan_blocks(const int* __restrict__ work, int* __restrict__ bsum) {
    __shared__ int sd[256];
    int b = blockIdx.x, t = threadIdx.x;
    int base = b * 1024 + t * 4;
    int s = 0;
    #pragma unroll
    for (int j = 0; j < 4; ++j) {
        int i = base + j;
        if (i < N_NODES) s += work[i];
    }
    sd[t] = s; __syncthreads();
    for (int off = 128; off > 0; off >>= 1) {
        if (t < off) sd[t] += sd[t + off];
        __syncthreads();
    }
    if (t == 0) bsum[b] = sd[0];
}

__global__ __launch_bounds__(128)
void scan_top(int* __restrict__ bsum, int* __restrict__ offsets) {
    __shared__ int sd[128];
    int t = threadIdx.x;
    sd[t] = (t < SCAN_NBLK) ? bsum[t] : 0;
    __syncthreads();
    #pragma unroll
    for (int off = 1; off < 128; off <<= 1) {
        int v = (t >= off) ? sd[t - off] : 0;
        __syncthreads();
        sd[t] += v;
        __syncthreads();
    }
    int excl = (t > 0) ? sd[t - 1] : 0;
    if (t < SCAN_NBLK) bsum[t] = excl;
    if (t == 0) offsets[N_NODES] = N_EDGES;
}

__global__ __launch_bounds__(256)
void scan_down(int* __restrict__ work, const int* __restrict__ bsum,
               int* __restrict__ offsets, float* __restrict__ dinv) {
    __shared__ int sd[256];
    int b = blockIdx.x, t = threadIdx.x;
    int base = b * 1024 + t * 4;
    int d[4];
    int tsum = 0;
    #pragma unroll
    for (int j = 0; j < 4; ++j) {
        int i = base + j;
        d[j] = (i < N_NODES) ? work[i] : 0;
        tsum += d[j];
    }
    sd[t] = tsum; __syncthreads();
    #pragma unroll
    for (int off = 1; off < 256; off <<= 1) {
        int v = (t >= off) ? sd[t - off] : 0;
        __syncthreads();
        sd[t] += v;
        __syncthreads();
    }
    int run = bsum[b] + sd[t] - tsum;
    #pragma unroll
    for (int j = 0; j < 4; ++j) {
        int i = base + j;
        if (i < N_NODES) {
            offsets[i] = run;
            work[i] = run;                        // cursor
            dinv[i] = rsqrtf(1.0f + (float)d[j]);
            run += d[j];
        }
    }
}

// ---------------- CSR fill ----------------
__global__ __launch_bounds__(256)
void fill_csr(const int* __restrict__ rows, const int* __restrict__ cols,
              int* work, int* __restrict__ esrc, int nE) {
    int e = blockIdx.x * 256 + threadIdx.x;
    if (e >= nE) return;
    int p = atomicAdd(&work[cols[e]], 1);
    esrc[p] = rows[e];
}

// ---------------- x -> bf16 hi/lo split ----------------
__global__ __launch_bounds__(256)
void split_x(const float* __restrict__ x, ushort* __restrict__ xh, ushort* __restrict__ xl) {
    int i = blockIdx.x * 256 + threadIdx.x;      // float4 group index
    if (i >= N_NODES * D_FEAT / 4) return;
    float4 v = ((const float4*)x)[i];
    ushort4 h, l;
    h.x = f2b(v.x); l.x = f2b(v.x - b2f(h.x));
    h.y = f2b(v.y); l.y = f2b(v.y - b2f(h.y));
    h.z = f2b(v.z); l.z = f2b(v.z - b2f(h.z));
    h.w = f2b(v.w); l.w = f2b(v.w - b2f(h.w));
    ((ushort4*)xh)[i] = h;
    ((ushort4*)xl)[i] = l;
}

// ---------------- W1 -> fragment-ordered bf16 hi/lo ----------------
// layout: wf[((ks*16 + nb)*64 + lane)*8 + j], frag elem B[k=ks*32+quad*8+j][n=nb*16+m]
__global__ __launch_bounds__(256)
void fragw1(const float* __restrict__ W1, ushort* __restrict__ wfh, ushort* __restrict__ wfl) {
    int t = blockIdx.x * 256 + threadIdx.x;      // 8192 total
    int ks = t >> 10, nb = (t >> 6) & 15, lane = t & 63;
    int m = lane & 15, quad = lane >> 4;
    ushort h8[8], l8[8];
    #pragma unroll
    for (int j = 0; j < 8; ++j) {
        int k = ks * 32 + quad * 8 + j;
        float w = W1[k * HIDDEN + nb * 16 + m];
        h8[j] = f2b(w);
        l8[j] = f2b(w - b2f(h8[j]));
    }
    long off = ((long)(ks * 16 + nb) * 64 + lane) * 8;
    *(ushort4*)&wfh[off]     = make_ushort4(h8[0], h8[1], h8[2], h8[3]);
    *(ushort4*)&wfh[off + 4] = make_ushort4(h8[4], h8[5], h8[6], h8[7]);
    *(ushort4*)&wfl[off]     = make_ushort4(l8[0], l8[1], l8[2], l8[3]);
    *(ushort4*)&wfl[off + 4] = make_ushort4(l8[4], l8[5], l8[6], l8[7]);
}

// ---------------- W2 -> fragment-ordered bf16 (single) ----------------
__global__ __launch_bounds__(256)
void fragw2(const float* __restrict__ W2, ushort* __restrict__ wf) {
    int t = blockIdx.x * 256 + threadIdx.x;      // 2048 total
    int ks = t >> 8, nb = (t >> 6) & 3, lane = t & 63;
    int m = lane & 15, quad = lane >> 4;
    ushort h8[8];
    #pragma unroll
    for (int j = 0; j < 8; ++j) {
        int k = ks * 32 + quad * 8 + j;
        h8[j] = f2b(W2[k * N_CLASSES + nb * 16 + m]);
    }
    long off = ((long)(ks * 4 + nb) * 64 + lane) * 8;
    *(ushort4*)&wf[off]     = make_ushort4(h8[0], h8[1], h8[2], h8[3]);
    *(ushort4*)&wf[off + 4] = make_ushort4(h8[4], h8[5], h8[6], h8[7]);
}

// ---------------- GEMM1: hs = dinv[row] * (x @ W1), bf16 split 3-product ----
// block = 4 waves, 64 rows; wave -> 16 rows x 256 cols (16 nb frags)
__global__ __launch_bounds__(256)
void gemm1_mfma(const ushort* __restrict__ xh, const ushort* __restrict__ xl,
                const ushort* __restrict__ wfh, const ushort* __restrict__ wfl,
                const float* __restrict__ dinv, ushort* __restrict__ hs)
{
    int tid = threadIdx.x;
    int wm = tid >> 6, lane = tid & 63;
    int row0 = blockIdx.x * 64 + wm * 16;
    int m = lane & 15, quad = lane >> 4;
    long arow = row0 + m;

    f32x4 acc[16];
    #pragma unroll
    for (int nb = 0; nb < 16; ++nb) acc[nb] = (f32x4){0.f, 0.f, 0.f, 0.f};

    const ushort* aph = xh + arow * D_FEAT + quad * 8;
    const ushort* apl = xl + arow * D_FEAT + quad * 8;

    for (int ks = 0; ks < 8; ++ks) {
        bf16x8 ah = *(const bf16x8*)(aph + ks * 32);
        bf16x8 al = *(const bf16x8*)(apl + ks * 32);
        const ushort* bh = wfh + ((long)(ks * 16) * 64 + lane) * 8;
        const ushort* bl = wfl + ((long)(ks * 16) * 64 + lane) * 8;
        #pragma unroll
        for (int nb = 0; nb < 16; ++nb) {
            bf16x8 wbh = *(const bf16x8*)(bh + (long)nb * 64 * 8);
            bf16x8 wbl = *(const bf16x8*)(bl + (long)nb * 64 * 8);
            acc[nb] = __builtin_amdgcn_mfma_f32_16x16x32_bf16(ah, wbh, acc[nb], 0, 0, 0);
            acc[nb] = __builtin_amdgcn_mfma_f32_16x16x32_bf16(ah, wbl, acc[nb], 0, 0, 0);
            acc[nb] = __builtin_amdgcn_mfma_f32_16x16x32_bf16(al, wbh, acc[nb], 0, 0, 0);
        }
    }

    #pragma unroll
    for (int reg = 0; reg < 4; ++reg) {
        int row = row0 + quad * 4 + reg;
        if (row < N_NODES) {
            float dv = dinv[row];
            #pragma unroll
            for (int nb = 0; nb < 16; ++nb)
                hs[(long)row * HIDDEN + nb * 16 + m] = f2b(acc[nb][reg] * dv);
        }
    }
}

// ---------------- GEMM2: h2 = r1s @ W2 (bf16 single) ----------------
__global__ __launch_bounds__(256)
void gemm2_mfma(const ushort* __restrict__ r1s, const ushort* __restrict__ wf,
                ushort* __restrict__ h2)
{
    int tid = threadIdx.x;
    int wm = tid >> 6, lane = tid & 63;
    int row0 = blockIdx.x * 64 + wm * 16;
    int m = lane & 15, quad = lane >> 4;
    long arow = row0 + m;

    f32x4 acc[4];
    #pragma unroll
    for (int nb = 0; nb < 4; ++nb) acc[nb] = (f32x4){0.f, 0.f, 0.f, 0.f};

    const ushort* ap = r1s + arow * HIDDEN + quad * 8;

    for (int ks = 0; ks < 8; ++ks) {
        bf16x8 a = *(const bf16x8*)(ap + ks * 32);
        const ushort* bp = wf + ((long)(ks * 4) * 64 + lane) * 8;
        #pragma unroll
        for (int nb = 0; nb < 4; ++nb) {
            bf16x8 b = *(const bf16x8*)(bp + (long)nb * 64 * 8);
            acc[nb] = __builtin_amdgcn_mfma_f32_16x16x32_bf16(a, b, acc[nb], 0, 0, 0);
        }
    }

    #pragma unroll
    for (int reg = 0; reg < 4; ++reg) {
        int row = row0 + quad * 4 + reg;
        if (row < N_NODES) {
            #pragma unroll
            for (int nb = 0; nb < 4; ++nb)
                h2[(long)row * N_CLASSES + nb * 16 + m] = f2b(acc[nb][reg]);
        }
    }
}

// ---------------- aggregate 256 feats bf16: r1s = dinv*relu(dinv*agg + b1) --
__global__ __launch_bounds__(256)
void agg256(const ushort* __restrict__ src, const int* __restrict__ offsets,
            const int* __restrict__ esrc, const float* __restrict__ dinv,
            const float* __restrict__ b1, ushort* __restrict__ dst)
{
    int wave = threadIdx.x >> 6, lane = threadIdx.x & 63;
    int v = blockIdx.x * 4 + wave;
    int c = lane << 2;
    ushort4 s = *(const ushort4*)&src[(long)v * 256 + c];
    float a0 = b2f(s.x), a1 = b2f(s.y), a2 = b2f(s.z), a3 = b2f(s.w);
    int e = offsets[v], end = offsets[v + 1];
    for (; e + 4 <= end; e += 4) {
        int s0 = esrc[e], s1 = esrc[e + 1], s2 = esrc[e + 2], s3 = esrc[e + 3];
        ushort4 u0 = *(const ushort4*)&src[(long)s0 * 256 + c];
        ushort4 u1 = *(const ushort4*)&src[(long)s1 * 256 + c];
        ushort4 u2 = *(const ushort4*)&src[(long)s2 * 256 + c];
        ushort4 u3 = *(const ushort4*)&src[(long)s3 * 256 + c];
        a0 += (b2f(u0.x) + b2f(u1.x)) + (b2f(u2.x) + b2f(u3.x));
        a1 += (b2f(u0.y) + b2f(u1.y)) + (b2f(u2.y) + b2f(u3.y));
        a2 += (b2f(u0.z) + b2f(u1.z)) + (b2f(u2.z) + b2f(u3.z));
        a3 += (b2f(u0.w) + b2f(u1.w)) + (b2f(u2.w) + b2f(u3.w));
    }
    for (; e < end; ++e) {
        ushort4 u = *(const ushort4*)&src[(long)esrc[e] * 256 + c];
        a0 += b2f(u.x); a1 += b2f(u.y); a2 += b2f(u.z); a3 += b2f(u.w);
    }
    float dv = dinv[v];
    float4 bb = *(const float4*)&b1[c];
    float r0 = dv * fmaxf(fmaf(dv, a0, bb.x), 0.f);
    float r1 = dv * fmaxf(fmaf(dv, a1, bb.y), 0.f);
    float r2 = dv * fmaxf(fmaf(dv, a2, bb.z), 0.f);
    float r3 = dv * fmaxf(fmaf(dv, a3, bb.w), 0.f);
    *(ushort4*)&dst[(long)v * 256 + c] = make_ushort4(f2b(r0), f2b(r1), f2b(r2), f2b(r3));
}

// ---------------- aggregate 64 feats bf16 -> fp32 out ----------------
__global__ __launch_bounds__(256)
void agg64b(const ushort* __restrict__ src, const int* __restrict__ offsets,
            const int* __restrict__ esrc, const float* __restrict__ dinv,
            const float* __restrict__ b2, float* __restrict__ out)
{
    int wave = threadIdx.x >> 6, lane = threadIdx.x & 63;
    int v = blockIdx.x * 4 + wave;
    float acc = b2f(src[(long)v * 64 + lane]);
    int e = offsets[v], end = offsets[v + 1];
    for (; e + 4 <= end; e += 4) {
        int s0 = esrc[e], s1 = esrc[e + 1], s2 = esrc[e + 2], s3 = esrc[e + 3];
        float a0 = b2f(src[(long)s0 * 64 + lane]);
        float a1 = b2f(src[(long)s1 * 64 + lane]);
        float a2 = b2f(src[(long)s2 * 64 + lane]);
        float a3 = b2f(src[(long)s3 * 64 + lane]);
        acc += (a0 + a1) + (a2 + a3);
    }
    for (; e < end; ++e) acc += b2f(src[(long)esrc[e] * 64 + lane]);
    out[(long)v * 64 + lane] = fmaf(dinv[v], acc, b2[lane]);
}

// ---------------- workspace layout (bytes, all 16-aligned) ----------------
#define WS_DINV   0UL
#define WS_OFFS   524288UL
#define WS_WORK   1048576UL
#define WS_BSUM   1572864UL
#define WS_ESRC   2097152UL        // 6.4 MB
#define WS_XH     8912896UL        // 100032 x 256 bf16 = 51,216,384   (later: h2)
#define WS_XL     60129280UL       // 100032 x 256 bf16                (later: r1s)
#define WS_WF1H   111345664UL      // 131072
#define WS_WF1L   111476736UL      // 131072
#define WS_WF2    111607808UL      // 32768
#define WS_HS1    111640576UL      // 100032 x 256 bf16 -> end 162,856,960

extern "C" void kernel_launch(void* const* d_in, const int* in_sizes, int n_in,
                              void* d_out, int out_size, void* d_ws, size_t ws_size,
                              hipStream_t stream)
{
    const float* x  = (const float*)d_in[0];
    const int*   ei = (const int*)d_in[1];
    const float* W1 = (const float*)d_in[2];
    const float* b1 = (const float*)d_in[3];
    const float* W2 = (const float*)d_in[4];
    const float* b2 = (const float*)d_in[5];
    float* out = (float*)d_out;

    const int* rows = ei;            // sources
    const int* cols = ei + N_EDGES;  // targets

    char* ws = (char*)d_ws;
    float*  dinv    = (float*)(ws + WS_DINV);
    int*    offsets = (int*)(ws + WS_OFFS);
    int*    work    = (int*)(ws + WS_WORK);
    int*    bsum    = (int*)(ws + WS_BSUM);
    int*    esrc    = (int*)(ws + WS_ESRC);
    ushort* xh      = (ushort*)(ws + WS_XH);
    ushort* xl      = (ushort*)(ws + WS_XL);
    ushort* wf1h    = (ushort*)(ws + WS_WF1H);
    ushort* wf1l    = (ushort*)(ws + WS_WF1L);
    ushort* wf2     = (ushort*)(ws + WS_WF2);
    ushort* hs1     = (ushort*)(ws + WS_HS1);
    ushort* r1s     = xl;            // alias: xl dead after gemm1
    ushort* h2      = xh;            // alias: xh dead after gemm1

    // --- CSR build ---
    init_work<<<(N_NODES + 255) / 256, 256, 0, stream>>>(work, N_NODES);
    count_deg<<<(N_EDGES + 255) / 256, 256, 0, stream>>>(cols, work, N_EDGES);
    scan_blocks<<<SCAN_NBLK, 256, 0, stream>>>(work, bsum);
    scan_top<<<1, 128, 0, stream>>>(bsum, offsets);
    scan_down<<<SCAN_NBLK, 256, 0, stream>>>(work, bsum, offsets, dinv);
    fill_csr<<<(N_EDGES + 255) / 256, 256, 0, stream>>>(rows, cols, work, esrc, N_EDGES);

    // --- precision prep ---
    split_x<<<(N_NODES * D_FEAT / 4 + 255) / 256, 256, 0, stream>>>(x, xh, xl);
    fragw1<<<32, 256, 0, stream>>>(W1, wf1h, wf1l);
    fragw2<<<8, 256, 0, stream>>>(W2, wf2);

    const int gemm_grid = (N_NODES + 63) / 64;   // 1563
    const int agg_grid  = N_NODES / 4;

    // --- layer 1 ---
    gemm1_mfma<<<gemm_grid, 256, 0, stream>>>(xh, xl, wf1h, wf1l, dinv, hs1);
    agg256<<<agg_grid, 256, 0, stream>>>(hs1, offsets, esrc, dinv, b1, r1s);

    // --- layer 2 ---
    gemm2_mfma<<<gemm_grid, 256, 0, stream>>>(r1s, wf2, h2);
    agg64b<<<agg_grid, 256, 0, stream>>>(h2, offsets, esrc, dinv, b2, out);
}

// Round 6
// 525.811 us; speedup vs baseline: 13.6758x; 1.2757x over previous
//
#include <hip/hip_runtime.h>
#include <hip/hip_bf16.h>

#define N_NODES 100000
#define N_PAD   100032          // padded rows for MFMA tiles (64-row blocks)
#define N_EDGES 1600000
#define D_FEAT 256
#define HIDDEN 256
#define N_CLASSES 64

#define NBKT 391                // buckets of 256 nodes: 99999>>8 = 390
#define TILE 4096               // edges per bin_scatter block
#define CAP  8192               // bucket_fill LDS staging (mean 4093, sigma 64)

typedef __attribute__((ext_vector_type(8))) short bf16x8;
typedef __attribute__((ext_vector_type(4))) float f32x4;

__device__ inline float b2f(ushort u) {
    unsigned v = ((unsigned)u) << 16;
    float f; __builtin_memcpy(&f, &v, 4); return f;
}
__device__ inline ushort f2b(float f) {   // RNE
    unsigned u; __builtin_memcpy(&u, &f, 4);
    unsigned r = (u + 0x7fffu + ((u >> 16) & 1u)) >> 16;
    return (ushort)r;
}

// ---------------- CSR build: bucketed two-phase ----------------
__global__ __launch_bounds__(256)
void zero_bcnt(int* bcnt) {
    int i = blockIdx.x * 256 + threadIdx.x;
    if (i < NBKT) bcnt[i] = 0;
}

__global__ __launch_bounds__(256)
void bin_count(const int* __restrict__ cols, int* bcnt, int nE) {
    __shared__ int h[NBKT];
    int t = threadIdx.x;
    for (int i = t; i < NBKT; i += 256) h[i] = 0;
    __syncthreads();
    for (long e = (long)blockIdx.x * 256 + t; e < nE; e += (long)gridDim.x * 256)
        atomicAdd(&h[cols[e] >> 8], 1);
    __syncthreads();
    for (int i = t; i < NBKT; i += 256)
        if (h[i]) atomicAdd(&bcnt[i], h[i]);
}

__global__ __launch_bounds__(256)
void bucket_scan(const int* __restrict__ bcnt, int* __restrict__ bbase,
                 int* __restrict__ bcur, int* __restrict__ offsets) {
    __shared__ int sd[256];
    int t = threadIdx.x;
    int i0 = 2 * t, i1 = 2 * t + 1;
    int a = (i0 < NBKT) ? bcnt[i0] : 0;
    int b = (i1 < NBKT) ? bcnt[i1] : 0;
    int s = a + b;
    sd[t] = s; __syncthreads();
    #pragma unroll
    for (int off = 1; off < 256; off <<= 1) {
        int v = (t >= off) ? sd[t - off] : 0;
        __syncthreads();
        sd[t] += v;
        __syncthreads();
    }
    int ex = sd[t] - s;
    if (i0 <= NBKT) bbase[i0] = ex;
    if (i0 < NBKT)  bcur[i0] = ex;
    if (i1 <= NBKT) bbase[i1] = ex + a;
    if (i1 < NBKT)  bcur[i1] = ex + a;
    if (t == 0) offsets[N_NODES] = N_EDGES;
}

// tile -> LDS sort by bucket -> batched reservation -> packed contiguous writes
__global__ __launch_bounds__(256)
void bin_scatter(const int* __restrict__ rows, const int* __restrict__ cols,
                 int* bcur, unsigned* __restrict__ bins, int nE)
{
    __shared__ unsigned recs[TILE];
    __shared__ ushort bos[TILE];
    __shared__ int hist[NBKT], excl[NBKT], cursor[NBKT], gbase[NBKT];
    __shared__ int sd[256];
    int t = threadIdx.x;
    long e0 = (long)blockIdx.x * TILE;
    int cnt = (int)min((long)TILE, (long)nE - e0);
    for (int i = t; i < NBKT; i += 256) hist[i] = 0;
    __syncthreads();
    int myrow[TILE / 256], mycol[TILE / 256];
    #pragma unroll
    for (int k = 0; k < TILE / 256; ++k) {
        int i = k * 256 + t;
        if (i < cnt) {
            myrow[k] = rows[e0 + i];
            mycol[k] = cols[e0 + i];
            atomicAdd(&hist[mycol[k] >> 8], 1);
        }
    }
    __syncthreads();
    // parallel exclusive scan of hist (2 buckets per thread)
    {
        int i0 = 2 * t, i1 = 2 * t + 1;
        int a = (i0 < NBKT) ? hist[i0] : 0;
        int b = (i1 < NBKT) ? hist[i1] : 0;
        int s = a + b;
        sd[t] = s; __syncthreads();
        #pragma unroll
        for (int off = 1; off < 256; off <<= 1) {
            int v = (t >= off) ? sd[t - off] : 0;
            __syncthreads();
            sd[t] += v;
            __syncthreads();
        }
        int ex = sd[t] - s;
        if (i0 < NBKT) { excl[i0] = ex;     cursor[i0] = ex; }
        if (i1 < NBKT) { excl[i1] = ex + a; cursor[i1] = ex + a; }
    }
    __syncthreads();
    #pragma unroll
    for (int k = 0; k < TILE / 256; ++k) {
        int i = k * 256 + t;
        if (i < cnt) {
            int b = mycol[k] >> 8;
            int s = atomicAdd(&cursor[b], 1);
            // unsigned pack: high 8 bits = node-within-bucket, low 24 = source row
            recs[s] = ((unsigned)(mycol[k] & 255) << 24) | (unsigned)myrow[k];
            bos[s] = (ushort)b;
        }
    }
    __syncthreads();
    for (int i = t; i < NBKT; i += 256)
        if (hist[i] > 0) gbase[i] = atomicAdd(&bcur[i], hist[i]);
    __syncthreads();
    for (int i = t; i < cnt; i += 256) {
        int b = bos[i];
        bins[gbase[b] + (i - excl[b])] = recs[i];
    }
}

// one block per bucket: degrees -> dinv/offsets; LDS-staged coalesced esrc
__global__ __launch_bounds__(256)
void bucket_fill(const unsigned* __restrict__ bins, const int* __restrict__ bbase,
                 int* __restrict__ offsets, float* __restrict__ dinv,
                 int* __restrict__ esrc)
{
    int b = blockIdx.x, t = threadIdx.x;
    int s0 = bbase[b], s1 = bbase[b + 1];
    int len = s1 - s0;
    __shared__ int cnt[256];
    __shared__ int sd[256];
    __shared__ int cur[256];
    __shared__ int stage[CAP];
    cnt[t] = 0;
    __syncthreads();
    for (int i = t; i < len; i += 256) atomicAdd(&cnt[bins[s0 + i] >> 24], 1);
    __syncthreads();
    int c = cnt[t];
    sd[t] = c; __syncthreads();
    #pragma unroll
    for (int off = 1; off < 256; off <<= 1) {
        int v = (t >= off) ? sd[t - off] : 0;
        __syncthreads();
        sd[t] += v;
        __syncthreads();
    }
    int ex = sd[t] - c;
    cur[t] = ex;
    int node = b * 256 + t;
    if (node < N_NODES) {
        offsets[node] = s0 + ex;
        dinv[node] = rsqrtf(1.0f + (float)c);
    }
    __syncthreads();
    if (len <= CAP) {
        for (int i = t; i < len; i += 256) {
            unsigned r = bins[s0 + i];
            int p = atomicAdd(&cur[r >> 24], 1);
            stage[p] = (int)(r & 0xFFFFFFu);
        }
        __syncthreads();
        for (int i = t; i < len; i += 256) esrc[s0 + i] = stage[i];
    } else {   // statistically unreachable fallback (correctness guard)
        for (int i = t; i < len; i += 256) {
            unsigned r = bins[s0 + i];
            int p = atomicAdd(&cur[r >> 24], 1);
            esrc[s0 + p] = (int)(r & 0xFFFFFFu);
        }
    }
}

// ---------------- x -> bf16 hi/lo split ----------------
__global__ __launch_bounds__(256)
void split_x(const float* __restrict__ x, ushort* __restrict__ xh, ushort* __restrict__ xl) {
    int i = blockIdx.x * 256 + threadIdx.x;      // float4 group index
    if (i >= N_NODES * D_FEAT / 4) return;
    float4 v = ((const float4*)x)[i];
    ushort4 h, l;
    h.x = f2b(v.x); l.x = f2b(v.x - b2f(h.x));
    h.y = f2b(v.y); l.y = f2b(v.y - b2f(h.y));
    h.z = f2b(v.z); l.z = f2b(v.z - b2f(h.z));
    h.w = f2b(v.w); l.w = f2b(v.w - b2f(h.w));
    ((ushort4*)xh)[i] = h;
    ((ushort4*)xl)[i] = l;
}

// ---------------- W1 -> fragment-ordered bf16 hi/lo ----------------
__global__ __launch_bounds__(256)
void fragw1(const float* __restrict__ W1, ushort* __restrict__ wfh, ushort* __restrict__ wfl) {
    int t = blockIdx.x * 256 + threadIdx.x;      // 8192 total
    int ks = t >> 10, nb = (t >> 6) & 15, lane = t & 63;
    int m = lane & 15, quad = lane >> 4;
    ushort h8[8], l8[8];
    #pragma unroll
    for (int j = 0; j < 8; ++j) {
        int k = ks * 32 + quad * 8 + j;
        float w = W1[k * HIDDEN + nb * 16 + m];
        h8[j] = f2b(w);
        l8[j] = f2b(w - b2f(h8[j]));
    }
    long off = ((long)(ks * 16 + nb) * 64 + lane) * 8;
    *(ushort4*)&wfh[off]     = make_ushort4(h8[0], h8[1], h8[2], h8[3]);
    *(ushort4*)&wfh[off + 4] = make_ushort4(h8[4], h8[5], h8[6], h8[7]);
    *(ushort4*)&wfl[off]     = make_ushort4(l8[0], l8[1], l8[2], l8[3]);
    *(ushort4*)&wfl[off + 4] = make_ushort4(l8[4], l8[5], l8[6], l8[7]);
}

// ---------------- W2 -> fragment-ordered bf16 (single) ----------------
__global__ __launch_bounds__(256)
void fragw2(const float* __restrict__ W2, ushort* __restrict__ wf) {
    int t = blockIdx.x * 256 + threadIdx.x;      // 2048 total
    int ks = t >> 8, nb = (t >> 6) & 3, lane = t & 63;
    int m = lane & 15, quad = lane >> 4;
    ushort h8[8];
    #pragma unroll
    for (int j = 0; j < 8; ++j) {
        int k = ks * 32 + quad * 8 + j;
        h8[j] = f2b(W2[k * N_CLASSES + nb * 16 + m]);
    }
    long off = ((long)(ks * 4 + nb) * 64 + lane) * 8;
    *(ushort4*)&wf[off]     = make_ushort4(h8[0], h8[1], h8[2], h8[3]);
    *(ushort4*)&wf[off + 4] = make_ushort4(h8[4], h8[5], h8[6], h8[7]);
}

// ---------------- GEMM1: hs = dinv[row] * (x @ W1), bf16 split 3-product ----
__global__ __launch_bounds__(256)
void gemm1_mfma(const ushort* __restrict__ xh, const ushort* __restrict__ xl,
                const ushort* __restrict__ wfh, const ushort* __restrict__ wfl,
                const float* __restrict__ dinv, ushort* __restrict__ hs)
{
    int tid = threadIdx.x;
    int wm = tid >> 6, lane = tid & 63;
    int row0 = blockIdx.x * 64 + wm * 16;
    int m = lane & 15, quad = lane >> 4;
    long arow = row0 + m;

    f32x4 acc[16];
    #pragma unroll
    for (int nb = 0; nb < 16; ++nb) acc[nb] = (f32x4){0.f, 0.f, 0.f, 0.f};

    const ushort* aph = xh + arow * D_FEAT + quad * 8;
    const ushort* apl = xl + arow * D_FEAT + quad * 8;

    for (int ks = 0; ks < 8; ++ks) {
        bf16x8 ah = *(const bf16x8*)(aph + ks * 32);
        bf16x8 al = *(const bf16x8*)(apl + ks * 32);
        const ushort* bh = wfh + ((long)(ks * 16) * 64 + lane) * 8;
        const ushort* bl = wfl + ((long)(ks * 16) * 64 + lane) * 8;
        #pragma unroll
        for (int nb = 0; nb < 16; ++nb) {
            bf16x8 wbh = *(const bf16x8*)(bh + (long)nb * 64 * 8);
            bf16x8 wbl = *(const bf16x8*)(bl + (long)nb * 64 * 8);
            acc[nb] = __builtin_amdgcn_mfma_f32_16x16x32_bf16(ah, wbh, acc[nb], 0, 0, 0);
            acc[nb] = __builtin_amdgcn_mfma_f32_16x16x32_bf16(ah, wbl, acc[nb], 0, 0, 0);
            acc[nb] = __builtin_amdgcn_mfma_f32_16x16x32_bf16(al, wbh, acc[nb], 0, 0, 0);
        }
    }

    #pragma unroll
    for (int reg = 0; reg < 4; ++reg) {
        int row = row0 + quad * 4 + reg;
        if (row < N_NODES) {
            float dv = dinv[row];
            #pragma unroll
            for (int nb = 0; nb < 16; ++nb)
                hs[(long)row * HIDDEN + nb * 16 + m] = f2b(acc[nb][reg] * dv);
        }
    }
}

// ---------------- GEMM2: h2 = r1s @ W2 (bf16 single) ----------------
__global__ __launch_bounds__(256)
void gemm2_mfma(const ushort* __restrict__ r1s, const ushort* __restrict__ wf,
                ushort* __restrict__ h2)
{
    int tid = threadIdx.x;
    int wm = tid >> 6, lane = tid & 63;
    int row0 = blockIdx.x * 64 + wm * 16;
    int m = lane & 15, quad = lane >> 4;
    long arow = row0 + m;

    f32x4 acc[4];
    #pragma unroll
    for (int nb = 0; nb < 4; ++nb) acc[nb] = (f32x4){0.f, 0.f, 0.f, 0.f};

    const ushort* ap = r1s + arow * HIDDEN + quad * 8;

    for (int ks = 0; ks < 8; ++ks) {
        bf16x8 a = *(const bf16x8*)(ap + ks * 32);
        const ushort* bp = wf + ((long)(ks * 4) * 64 + lane) * 8;
        #pragma unroll
        for (int nb = 0; nb < 4; ++nb) {
            bf16x8 b = *(const bf16x8*)(bp + (long)nb * 64 * 8);
            acc[nb] = __builtin_amdgcn_mfma_f32_16x16x32_bf16(a, b, acc[nb], 0, 0, 0);
        }
    }

    #pragma unroll
    for (int reg = 0; reg < 4; ++reg) {
        int row = row0 + quad * 4 + reg;
        if (row < N_NODES) {
            #pragma unroll
            for (int nb = 0; nb < 4; ++nb)
                h2[(long)row * N_CLASSES + nb * 16 + m] = f2b(acc[nb][reg]);
        }
    }
}

// ---------------- aggregate 256 feats bf16: r1s = dinv*relu(dinv*agg + b1) --
__global__ __launch_bounds__(256)
void agg256(const ushort* __restrict__ src, const int* __restrict__ offsets,
            const int* __restrict__ esrc, const float* __restrict__ dinv,
            const float* __restrict__ b1, ushort* __restrict__ dst)
{
    int wave = threadIdx.x >> 6, lane = threadIdx.x & 63;
    int v = blockIdx.x * 4 + wave;
    int c = lane << 2;
    ushort4 s = *(const ushort4*)&src[(long)v * 256 + c];
    float a0 = b2f(s.x), a1 = b2f(s.y), a2 = b2f(s.z), a3 = b2f(s.w);
    int e = offsets[v], end = offsets[v + 1];
    for (; e + 4 <= end; e += 4) {
        int s0 = esrc[e], s1 = esrc[e + 1], s2 = esrc[e + 2], s3 = esrc[e + 3];
        ushort4 u0 = *(const ushort4*)&src[(long)s0 * 256 + c];
        ushort4 u1 = *(const ushort4*)&src[(long)s1 * 256 + c];
        ushort4 u2 = *(const ushort4*)&src[(long)s2 * 256 + c];
        ushort4 u3 = *(const ushort4*)&src[(long)s3 * 256 + c];
        a0 += (b2f(u0.x) + b2f(u1.x)) + (b2f(u2.x) + b2f(u3.x));
        a1 += (b2f(u0.y) + b2f(u1.y)) + (b2f(u2.y) + b2f(u3.y));
        a2 += (b2f(u0.z) + b2f(u1.z)) + (b2f(u2.z) + b2f(u3.z));
        a3 += (b2f(u0.w) + b2f(u1.w)) + (b2f(u2.w) + b2f(u3.w));
    }
    for (; e < end; ++e) {
        ushort4 u = *(const ushort4*)&src[(long)esrc[e] * 256 + c];
        a0 += b2f(u.x); a1 += b2f(u.y); a2 += b2f(u.z); a3 += b2f(u.w);
    }
    float dv = dinv[v];
    float4 bb = *(const float4*)&b1[c];
    float r0 = dv * fmaxf(fmaf(dv, a0, bb.x), 0.f);
    float r1 = dv * fmaxf(fmaf(dv, a1, bb.y), 0.f);
    float r2 = dv * fmaxf(fmaf(dv, a2, bb.z), 0.f);
    float r3 = dv * fmaxf(fmaf(dv, a3, bb.w), 0.f);
    *(ushort4*)&dst[(long)v * 256 + c] = make_ushort4(f2b(r0), f2b(r1), f2b(r2), f2b(r3));
}

// ---------------- aggregate 64 feats bf16 -> fp32 out ----------------
__global__ __launch_bounds__(256)
void agg64b(const ushort* __restrict__ src, const int* __restrict__ offsets,
            const int* __restrict__ esrc, const float* __restrict__ dinv,
            const float* __restrict__ b2, float* __restrict__ out)
{
    int wave = threadIdx.x >> 6, lane = threadIdx.x & 63;
    int v = blockIdx.x * 4 + wave;
    float acc = b2f(src[(long)v * 64 + lane]);
    int e = offsets[v], end = offsets[v + 1];
    for (; e + 4 <= end; e += 4) {
        int s0 = esrc[e], s1 = esrc[e + 1], s2 = esrc[e + 2], s3 = esrc[e + 3];
        float a0 = b2f(src[(long)s0 * 64 + lane]);
        float a1 = b2f(src[(long)s1 * 64 + lane]);
        float a2 = b2f(src[(long)s2 * 64 + lane]);
        float a3 = b2f(src[(long)s3 * 64 + lane]);
        acc += (a0 + a1) + (a2 + a3);
    }
    for (; e < end; ++e) acc += b2f(src[(long)esrc[e] * 64 + lane]);
    out[(long)v * 64 + lane] = fmaf(dinv[v], acc, b2[lane]);
}

// ---------------- workspace layout (bytes, 16-aligned) ----------------
#define WS_DINV   0UL            // 400,000
#define WS_OFFS   524288UL       // 400,004
#define WS_BCNT   1048576UL      // 391*4
#define WS_BBASE  1052672UL      // 392*4
#define WS_BCUR   1056768UL      // 391*4
#define WS_ESRC   1064960UL      // 6,400,000
#define WS_BINS   7602176UL      // 6,400,000
#define WS_XH     20447232UL     // 100032*256*2 = 51,216,384   (later: h2)
#define WS_XL     71663616UL     // 51,216,384                  (later: r1s)
#define WS_WF1H   122880000UL    // 131,072
#define WS_WF1L   123011072UL    // 131,072
#define WS_WF2    123142144UL    // 32,768
#define WS_HS1    123174912UL    // 51,216,384 -> end 174,391,296

extern "C" void kernel_launch(void* const* d_in, const int* in_sizes, int n_in,
                              void* d_out, int out_size, void* d_ws, size_t ws_size,
                              hipStream_t stream)
{
    const float* x  = (const float*)d_in[0];
    const int*   ei = (const int*)d_in[1];
    const float* W1 = (const float*)d_in[2];
    const float* b1 = (const float*)d_in[3];
    const float* W2 = (const float*)d_in[4];
    const float* b2 = (const float*)d_in[5];
    float* out = (float*)d_out;

    const int* rows = ei;            // sources
    const int* cols = ei + N_EDGES;  // targets

    char* ws = (char*)d_ws;
    float*    dinv    = (float*)(ws + WS_DINV);
    int*      offsets = (int*)(ws + WS_OFFS);
    int*      bcnt    = (int*)(ws + WS_BCNT);
    int*      bbase   = (int*)(ws + WS_BBASE);
    int*      bcur    = (int*)(ws + WS_BCUR);
    int*      esrc    = (int*)(ws + WS_ESRC);
    unsigned* bins    = (unsigned*)(ws + WS_BINS);
    ushort*   xh      = (ushort*)(ws + WS_XH);
    ushort*   xl      = (ushort*)(ws + WS_XL);
    ushort*   wf1h    = (ushort*)(ws + WS_WF1H);
    ushort*   wf1l    = (ushort*)(ws + WS_WF1L);
    ushort*   wf2     = (ushort*)(ws + WS_WF2);
    ushort*   hs1     = (ushort*)(ws + WS_HS1);
    ushort*   r1s     = xl;          // alias: xl dead after gemm1
    ushort*   h2      = xh;          // alias: xh dead after gemm1

    // --- CSR build (bucketed) ---
    zero_bcnt<<<2, 256, 0, stream>>>(bcnt);
    bin_count<<<512, 256, 0, stream>>>(cols, bcnt, N_EDGES);
    bucket_scan<<<1, 256, 0, stream>>>(bcnt, bbase, bcur, offsets);
    bin_scatter<<<(N_EDGES + TILE - 1) / TILE, 256, 0, stream>>>(rows, cols, bcur, bins, N_EDGES);
    bucket_fill<<<NBKT, 256, 0, stream>>>(bins, bbase, offsets, dinv, esrc);

    // --- precision prep ---
    split_x<<<(N_NODES * D_FEAT / 4 + 255) / 256, 256, 0, stream>>>(x, xh, xl);
    fragw1<<<32, 256, 0, stream>>>(W1, wf1h, wf1l);
    fragw2<<<8, 256, 0, stream>>>(W2, wf2);

    const int gemm_grid = (N_NODES + 63) / 64;   // 1563
    const int agg_grid  = N_NODES / 4;

    // --- layer 1 ---
    gemm1_mfma<<<gemm_grid, 256, 0, stream>>>(xh, xl, wf1h, wf1l, dinv, hs1);
    agg256<<<agg_grid, 256, 0, stream>>>(hs1, offsets, esrc, dinv, b1, r1s);

    // --- layer 2 ---
    gemm2_mfma<<<gemm_grid, 256, 0, stream>>>(r1s, wf2, h2);
    agg64b<<<agg_grid, 256, 0, stream>>>(h2, offsets, esrc, dinv, b2, out);
}

// Round 7
// 511.716 us; speedup vs baseline: 14.0525x; 1.0275x over previous
//
#include <hip/hip_runtime.h>
#include <hip/hip_bf16.h>

#define N_NODES 100000
#define N_PAD   100032          // padded rows for MFMA tiles
#define N_EDGES 1600000
#define D_FEAT 256
#define HIDDEN 256
#define N_CLASSES 64

#define NBKT 391                // buckets of 256 nodes: 99999>>8 = 390
#define TILE 4096               // edges per bin_scatter block
#define CAP  8192               // bucket_fill LDS staging (mean 4093, sigma 64)

typedef __attribute__((ext_vector_type(8))) short bf16x8;
typedef __attribute__((ext_vector_type(4))) float f32x4;

__device__ inline float b2f(ushort u) {
    unsigned v = ((unsigned)u) << 16;
    float f; __builtin_memcpy(&f, &v, 4); return f;
}
__device__ inline ushort f2b(float f) {   // RNE
    unsigned u; __builtin_memcpy(&u, &f, 4);
    unsigned r = (u + 0x7fffu + ((u >> 16) & 1u)) >> 16;
    return (ushort)r;
}

// ---------------- CSR build: bucketed two-phase ----------------
__global__ __launch_bounds__(256)
void zero_bcnt(int* bcnt) {
    int i = blockIdx.x * 256 + threadIdx.x;
    if (i < NBKT) bcnt[i] = 0;
}

__global__ __launch_bounds__(256)
void bin_count(const int* __restrict__ cols, int* bcnt, int nE) {
    __shared__ int h[NBKT];
    int t = threadIdx.x;
    for (int i = t; i < NBKT; i += 256) h[i] = 0;
    __syncthreads();
    for (long e = (long)blockIdx.x * 256 + t; e < nE; e += (long)gridDim.x * 256)
        atomicAdd(&h[cols[e] >> 8], 1);
    __syncthreads();
    for (int i = t; i < NBKT; i += 256)
        if (h[i]) atomicAdd(&bcnt[i], h[i]);
}

__global__ __launch_bounds__(256)
void bucket_scan(const int* __restrict__ bcnt, int* __restrict__ bbase,
                 int* __restrict__ bcur, int* __restrict__ offsets) {
    __shared__ int sd[256];
    int t = threadIdx.x;
    int i0 = 2 * t, i1 = 2 * t + 1;
    int a = (i0 < NBKT) ? bcnt[i0] : 0;
    int b = (i1 < NBKT) ? bcnt[i1] : 0;
    int s = a + b;
    sd[t] = s; __syncthreads();
    #pragma unroll
    for (int off = 1; off < 256; off <<= 1) {
        int v = (t >= off) ? sd[t - off] : 0;
        __syncthreads();
        sd[t] += v;
        __syncthreads();
    }
    int ex = sd[t] - s;
    if (i0 <= NBKT) bbase[i0] = ex;
    if (i0 < NBKT)  bcur[i0] = ex;
    if (i1 <= NBKT) bbase[i1] = ex + a;
    if (i1 < NBKT)  bcur[i1] = ex + a;
    if (t == 0) offsets[N_NODES] = N_EDGES;
}

// tile -> LDS sort by bucket -> batched reservation -> packed contiguous writes
__global__ __launch_bounds__(256)
void bin_scatter(const int* __restrict__ rows, const int* __restrict__ cols,
                 int* bcur, unsigned* __restrict__ bins, int nE)
{
    __shared__ unsigned recs[TILE];
    __shared__ ushort bos[TILE];
    __shared__ int hist[NBKT], excl[NBKT], cursor[NBKT], gbase[NBKT];
    __shared__ int sd[256];
    int t = threadIdx.x;
    long e0 = (long)blockIdx.x * TILE;
    int cnt = (int)min((long)TILE, (long)nE - e0);
    for (int i = t; i < NBKT; i += 256) hist[i] = 0;
    __syncthreads();
    int myrow[TILE / 256], mycol[TILE / 256];
    #pragma unroll
    for (int k = 0; k < TILE / 256; ++k) {
        int i = k * 256 + t;
        if (i < cnt) {
            myrow[k] = rows[e0 + i];
            mycol[k] = cols[e0 + i];
            atomicAdd(&hist[mycol[k] >> 8], 1);
        }
    }
    __syncthreads();
    {
        int i0 = 2 * t, i1 = 2 * t + 1;
        int a = (i0 < NBKT) ? hist[i0] : 0;
        int b = (i1 < NBKT) ? hist[i1] : 0;
        int s = a + b;
        sd[t] = s; __syncthreads();
        #pragma unroll
        for (int off = 1; off < 256; off <<= 1) {
            int v = (t >= off) ? sd[t - off] : 0;
            __syncthreads();
            sd[t] += v;
            __syncthreads();
        }
        int ex = sd[t] - s;
        if (i0 < NBKT) { excl[i0] = ex;     cursor[i0] = ex; }
        if (i1 < NBKT) { excl[i1] = ex + a; cursor[i1] = ex + a; }
    }
    __syncthreads();
    #pragma unroll
    for (int k = 0; k < TILE / 256; ++k) {
        int i = k * 256 + t;
        if (i < cnt) {
            int b = mycol[k] >> 8;
            int s = atomicAdd(&cursor[b], 1);
            recs[s] = ((unsigned)(mycol[k] & 255) << 24) | (unsigned)myrow[k];
            bos[s] = (ushort)b;
        }
    }
    __syncthreads();
    for (int i = t; i < NBKT; i += 256)
        if (hist[i] > 0) gbase[i] = atomicAdd(&bcur[i], hist[i]);
    __syncthreads();
    for (int i = t; i < cnt; i += 256) {
        int b = bos[i];
        bins[gbase[b] + (i - excl[b])] = recs[i];
    }
}

// one block per bucket: degrees -> dinv/offsets; LDS-staged coalesced esrc
__global__ __launch_bounds__(256)
void bucket_fill(const unsigned* __restrict__ bins, const int* __restrict__ bbase,
                 int* __restrict__ offsets, float* __restrict__ dinv,
                 int* __restrict__ esrc)
{
    int b = blockIdx.x, t = threadIdx.x;
    int s0 = bbase[b], s1 = bbase[b + 1];
    int len = s1 - s0;
    __shared__ int cnt[256];
    __shared__ int sd[256];
    __shared__ int cur[256];
    __shared__ int stage[CAP];
    cnt[t] = 0;
    __syncthreads();
    for (int i = t; i < len; i += 256) atomicAdd(&cnt[bins[s0 + i] >> 24], 1);
    __syncthreads();
    int c = cnt[t];
    sd[t] = c; __syncthreads();
    #pragma unroll
    for (int off = 1; off < 256; off <<= 1) {
        int v = (t >= off) ? sd[t - off] : 0;
        __syncthreads();
        sd[t] += v;
        __syncthreads();
    }
    int ex = sd[t] - c;
    cur[t] = ex;
    int node = b * 256 + t;
    if (node < N_NODES) {
        offsets[node] = s0 + ex;
        dinv[node] = rsqrtf(1.0f + (float)c);
    }
    __syncthreads();
    if (len <= CAP) {
        for (int i = t; i < len; i += 256) {
            unsigned r = bins[s0 + i];
            int p = atomicAdd(&cur[r >> 24], 1);
            stage[p] = (int)(r & 0xFFFFFFu);
        }
        __syncthreads();
        for (int i = t; i < len; i += 256) esrc[s0 + i] = stage[i];
    } else {   // statistically unreachable fallback (correctness guard)
        for (int i = t; i < len; i += 256) {
            unsigned r = bins[s0 + i];
            int p = atomicAdd(&cur[r >> 24], 1);
            esrc[s0 + p] = (int)(r & 0xFFFFFFu);
        }
    }
}

// ---------------- x -> bf16 hi/lo split ----------------
__global__ __launch_bounds__(256)
void split_x(const float* __restrict__ x, ushort* __restrict__ xh, ushort* __restrict__ xl) {
    int i = blockIdx.x * 256 + threadIdx.x;      // float4 group index
    if (i >= N_NODES * D_FEAT / 4) return;
    float4 v = ((const float4*)x)[i];
    ushort4 h, l;
    h.x = f2b(v.x); l.x = f2b(v.x - b2f(h.x));
    h.y = f2b(v.y); l.y = f2b(v.y - b2f(h.y));
    h.z = f2b(v.z); l.z = f2b(v.z - b2f(h.z));
    h.w = f2b(v.w); l.w = f2b(v.w - b2f(h.w));
    ((ushort4*)xh)[i] = h;
    ((ushort4*)xl)[i] = l;
}

// ---------------- W1 -> fragment-ordered bf16 hi/lo ----------------
__global__ __launch_bounds__(256)
void fragw1(const float* __restrict__ W1, ushort* __restrict__ wfh, ushort* __restrict__ wfl) {
    int t = blockIdx.x * 256 + threadIdx.x;      // 8192 total
    int ks = t >> 10, nb = (t >> 6) & 15, lane = t & 63;
    int m = lane & 15, quad = lane >> 4;
    ushort h8[8], l8[8];
    #pragma unroll
    for (int j = 0; j < 8; ++j) {
        int k = ks * 32 + quad * 8 + j;
        float w = W1[k * HIDDEN + nb * 16 + m];
        h8[j] = f2b(w);
        l8[j] = f2b(w - b2f(h8[j]));
    }
    long off = ((long)(ks * 16 + nb) * 64 + lane) * 8;
    *(ushort4*)&wfh[off]     = make_ushort4(h8[0], h8[1], h8[2], h8[3]);
    *(ushort4*)&wfh[off + 4] = make_ushort4(h8[4], h8[5], h8[6], h8[7]);
    *(ushort4*)&wfl[off]     = make_ushort4(l8[0], l8[1], l8[2], l8[3]);
    *(ushort4*)&wfl[off + 4] = make_ushort4(l8[4], l8[5], l8[6], l8[7]);
}

// ---------------- W2 -> fragment-ordered bf16 (single) ----------------
__global__ __launch_bounds__(256)
void fragw2(const float* __restrict__ W2, ushort* __restrict__ wf) {
    int t = blockIdx.x * 256 + threadIdx.x;      // 2048 total
    int ks = t >> 8, nb = (t >> 6) & 3, lane = t & 63;
    int m = lane & 15, quad = lane >> 4;
    ushort h8[8];
    #pragma unroll
    for (int j = 0; j < 8; ++j) {
        int k = ks * 32 + quad * 8 + j;
        h8[j] = f2b(W2[k * N_CLASSES + nb * 16 + m]);
    }
    long off = ((long)(ks * 4 + nb) * 64 + lane) * 8;
    *(ushort4*)&wf[off]     = make_ushort4(h8[0], h8[1], h8[2], h8[3]);
    *(ushort4*)&wf[off + 4] = make_ushort4(h8[4], h8[5], h8[6], h8[7]);
}

// ---------------- GEMM1: hs = dinv[row] * (x @ W1), bf16 split 3-product ----
// Rebalanced tiles: wave = 64 rows x 64 cols (4 m-frags x 4 nb-frags),
// block = 2x2 waves = 128 rows x 128 cols. B traffic/wave drops 256->64 KB.
__global__ __launch_bounds__(256)
void gemm1_mfma(const ushort* __restrict__ xh, const ushort* __restrict__ xl,
                const ushort* __restrict__ wfh, const ushort* __restrict__ wfl,
                const float* __restrict__ dinv, ushort* __restrict__ hs)
{
    int tid = threadIdx.x;
    int lane = tid & 63;
    int wm = (tid >> 6) & 1;                 // row-half of block
    int wn = tid >> 7;                       // col-half of block
    int row0 = blockIdx.y * 128 + wm * 64;
    int nb0 = blockIdx.x * 8 + wn * 4;       // nb in 16-col units
    int m = lane & 15, quad = lane >> 4;

    f32x4 acc[4][4];                          // [mf][nbl]
    #pragma unroll
    for (int i = 0; i < 4; ++i)
        #pragma unroll
        for (int j = 0; j < 4; ++j) acc[i][j] = (f32x4){0.f, 0.f, 0.f, 0.f};

    for (int ks = 0; ks < 8; ++ks) {
        bf16x8 ah[4], al[4];
        #pragma unroll
        for (int mf = 0; mf < 4; ++mf) {
            long r = (long)(row0 + mf * 16 + m);
            ah[mf] = *(const bf16x8*)(xh + r * D_FEAT + ks * 32 + quad * 8);
            al[mf] = *(const bf16x8*)(xl + r * D_FEAT + ks * 32 + quad * 8);
        }
        #pragma unroll
        for (int nbl = 0; nbl < 4; ++nbl) {
            long boff = ((long)(ks * 16 + nb0 + nbl) * 64 + lane) * 8;
            bf16x8 bh = *(const bf16x8*)(wfh + boff);
            bf16x8 bl = *(const bf16x8*)(wfl + boff);
            #pragma unroll
            for (int mf = 0; mf < 4; ++mf) {
                acc[mf][nbl] = __builtin_amdgcn_mfma_f32_16x16x32_bf16(ah[mf], bh, acc[mf][nbl], 0, 0, 0);
                acc[mf][nbl] = __builtin_amdgcn_mfma_f32_16x16x32_bf16(ah[mf], bl, acc[mf][nbl], 0, 0, 0);
                acc[mf][nbl] = __builtin_amdgcn_mfma_f32_16x16x32_bf16(al[mf], bh, acc[mf][nbl], 0, 0, 0);
            }
        }
    }

    #pragma unroll
    for (int mf = 0; mf < 4; ++mf)
        #pragma unroll
        for (int reg = 0; reg < 4; ++reg) {
            int row = row0 + mf * 16 + quad * 4 + reg;
            if (row < N_NODES) {
                float dv = dinv[row];
                #pragma unroll
                for (int nbl = 0; nbl < 4; ++nbl)
                    hs[(long)row * HIDDEN + (nb0 + nbl) * 16 + m] = f2b(acc[mf][nbl][reg] * dv);
            }
        }
}

// ---------------- GEMM2: h2 = r1s @ W2 (bf16 single) ----------------
// wave = 64 rows x 64 cols (4 m-frags x 4 nb); block = 4 waves = 256 rows.
__global__ __launch_bounds__(256)
void gemm2_mfma(const ushort* __restrict__ r1s, const ushort* __restrict__ wf,
                ushort* __restrict__ h2)
{
    int tid = threadIdx.x;
    int wv = tid >> 6, lane = tid & 63;
    int row0 = blockIdx.x * 256 + wv * 64;
    int m = lane & 15, quad = lane >> 4;

    f32x4 acc[4][4];
    #pragma unroll
    for (int i = 0; i < 4; ++i)
        #pragma unroll
        for (int j = 0; j < 4; ++j) acc[i][j] = (f32x4){0.f, 0.f, 0.f, 0.f};

    for (int ks = 0; ks < 8; ++ks) {
        bf16x8 a[4];
        #pragma unroll
        for (int mf = 0; mf < 4; ++mf) {
            long r = (long)(row0 + mf * 16 + m);
            a[mf] = *(const bf16x8*)(r1s + r * HIDDEN + ks * 32 + quad * 8);
        }
        #pragma unroll
        for (int nb = 0; nb < 4; ++nb) {
            bf16x8 b = *(const bf16x8*)(wf + ((long)(ks * 4 + nb) * 64 + lane) * 8);
            #pragma unroll
            for (int mf = 0; mf < 4; ++mf)
                acc[mf][nb] = __builtin_amdgcn_mfma_f32_16x16x32_bf16(a[mf], b, acc[mf][nb], 0, 0, 0);
        }
    }

    #pragma unroll
    for (int mf = 0; mf < 4; ++mf)
        #pragma unroll
        for (int reg = 0; reg < 4; ++reg) {
            int row = row0 + mf * 16 + quad * 4 + reg;
            if (row < N_NODES) {
                #pragma unroll
                for (int nb = 0; nb < 4; ++nb)
                    h2[(long)row * N_CLASSES + nb * 16 + m] = f2b(acc[mf][nb][reg]);
            }
        }
}

// ---------------- aggregate 256 feats bf16: r1s = dinv*relu(dinv*agg + b1) --
__global__ __launch_bounds__(256)
void agg256(const ushort* __restrict__ src, const int* __restrict__ offsets,
            const int* __restrict__ esrc, const float* __restrict__ dinv,
            const float* __restrict__ b1, ushort* __restrict__ dst)
{
    int wave = threadIdx.x >> 6, lane = threadIdx.x & 63;
    int v = blockIdx.x * 4 + wave;
    int c = lane << 2;
    ushort4 s = *(const ushort4*)&src[(long)v * 256 + c];
    float a0 = b2f(s.x), a1 = b2f(s.y), a2 = b2f(s.z), a3 = b2f(s.w);
    int e = offsets[v], end = offsets[v + 1];
    for (; e + 4 <= end; e += 4) {
        int s0 = esrc[e], s1 = esrc[e + 1], s2 = esrc[e + 2], s3 = esrc[e + 3];
        ushort4 u0 = *(const ushort4*)&src[(long)s0 * 256 + c];
        ushort4 u1 = *(const ushort4*)&src[(long)s1 * 256 + c];
        ushort4 u2 = *(const ushort4*)&src[(long)s2 * 256 + c];
        ushort4 u3 = *(const ushort4*)&src[(long)s3 * 256 + c];
        a0 += (b2f(u0.x) + b2f(u1.x)) + (b2f(u2.x) + b2f(u3.x));
        a1 += (b2f(u0.y) + b2f(u1.y)) + (b2f(u2.y) + b2f(u3.y));
        a2 += (b2f(u0.z) + b2f(u1.z)) + (b2f(u2.z) + b2f(u3.z));
        a3 += (b2f(u0.w) + b2f(u1.w)) + (b2f(u2.w) + b2f(u3.w));
    }
    for (; e < end; ++e) {
        ushort4 u = *(const ushort4*)&src[(long)esrc[e] * 256 + c];
        a0 += b2f(u.x); a1 += b2f(u.y); a2 += b2f(u.z); a3 += b2f(u.w);
    }
    float dv = dinv[v];
    float4 bb = *(const float4*)&b1[c];
    float r0 = dv * fmaxf(fmaf(dv, a0, bb.x), 0.f);
    float r1 = dv * fmaxf(fmaf(dv, a1, bb.y), 0.f);
    float r2 = dv * fmaxf(fmaf(dv, a2, bb.z), 0.f);
    float r3 = dv * fmaxf(fmaf(dv, a3, bb.w), 0.f);
    *(ushort4*)&dst[(long)v * 256 + c] = make_ushort4(f2b(r0), f2b(r1), f2b(r2), f2b(r3));
}

// ---------------- aggregate 64 feats bf16 -> fp32 out ----------------
__global__ __launch_bounds__(256)
void agg64b(const ushort* __restrict__ src, const int* __restrict__ offsets,
            const int* __restrict__ esrc, const float* __restrict__ dinv,
            const float* __restrict__ b2, float* __restrict__ out)
{
    int wave = threadIdx.x >> 6, lane = threadIdx.x & 63;
    int v = blockIdx.x * 4 + wave;
    float acc = b2f(src[(long)v * 64 + lane]);
    int e = offsets[v], end = offsets[v + 1];
    for (; e + 4 <= end; e += 4) {
        int s0 = esrc[e], s1 = esrc[e + 1], s2 = esrc[e + 2], s3 = esrc[e + 3];
        float a0 = b2f(src[(long)s0 * 64 + lane]);
        float a1 = b2f(src[(long)s1 * 64 + lane]);
        float a2 = b2f(src[(long)s2 * 64 + lane]);
        float a3 = b2f(src[(long)s3 * 64 + lane]);
        acc += (a0 + a1) + (a2 + a3);
    }
    for (; e < end; ++e) acc += b2f(src[(long)esrc[e] * 64 + lane]);
    out[(long)v * 64 + lane] = fmaf(dinv[v], acc, b2[lane]);
}

// ---------------- workspace layout (bytes, 16-aligned) ----------------
#define WS_DINV   0UL            // 400,000
#define WS_OFFS   524288UL       // 400,004
#define WS_BCNT   1048576UL      // 391*4
#define WS_BBASE  1052672UL      // 392*4
#define WS_BCUR   1056768UL      // 391*4
#define WS_ESRC   1064960UL      // 6,400,000
#define WS_BINS   7602176UL      // 6,400,000
#define WS_XH     20447232UL     // 100032*256*2 = 51,216,384   (later: h2)
#define WS_XL     71663616UL     // 51,216,384                  (later: r1s)
#define WS_WF1H   122880000UL    // 131,072
#define WS_WF1L   123011072UL    // 131,072
#define WS_WF2    123142144UL    // 32,768
#define WS_HS1    123174912UL    // 51,216,384 -> end 174,391,296

extern "C" void kernel_launch(void* const* d_in, const int* in_sizes, int n_in,
                              void* d_out, int out_size, void* d_ws, size_t ws_size,
                              hipStream_t stream)
{
    const float* x  = (const float*)d_in[0];
    const int*   ei = (const int*)d_in[1];
    const float* W1 = (const float*)d_in[2];
    const float* b1 = (const float*)d_in[3];
    const float* W2 = (const float*)d_in[4];
    const float* b2 = (const float*)d_in[5];
    float* out = (float*)d_out;

    const int* rows = ei;            // sources
    const int* cols = ei + N_EDGES;  // targets

    char* ws = (char*)d_ws;
    float*    dinv    = (float*)(ws + WS_DINV);
    int*      offsets = (int*)(ws + WS_OFFS);
    int*      bcnt    = (int*)(ws + WS_BCNT);
    int*      bbase   = (int*)(ws + WS_BBASE);
    int*      bcur    = (int*)(ws + WS_BCUR);
    int*      esrc    = (int*)(ws + WS_ESRC);
    unsigned* bins    = (unsigned*)(ws + WS_BINS);
    ushort*   xh      = (ushort*)(ws + WS_XH);
    ushort*   xl      = (ushort*)(ws + WS_XL);
    ushort*   wf1h    = (ushort*)(ws + WS_WF1H);
    ushort*   wf1l    = (ushort*)(ws + WS_WF1L);
    ushort*   wf2     = (ushort*)(ws + WS_WF2);
    ushort*   hs1     = (ushort*)(ws + WS_HS1);
    ushort*   r1s     = xl;          // alias: xl dead after gemm1
    ushort*   h2      = xh;          // alias: xh dead after gemm1

    // --- CSR build (bucketed) ---
    zero_bcnt<<<2, 256, 0, stream>>>(bcnt);
    bin_count<<<512, 256, 0, stream>>>(cols, bcnt, N_EDGES);
    bucket_scan<<<1, 256, 0, stream>>>(bcnt, bbase, bcur, offsets);
    bin_scatter<<<(N_EDGES + TILE - 1) / TILE, 256, 0, stream>>>(rows, cols, bcur, bins, N_EDGES);
    bucket_fill<<<NBKT, 256, 0, stream>>>(bins, bbase, offsets, dinv, esrc);

    // --- precision prep ---
    split_x<<<(N_NODES * D_FEAT / 4 + 255) / 256, 256, 0, stream>>>(x, xh, xl);
    fragw1<<<32, 256, 0, stream>>>(W1, wf1h, wf1l);
    fragw2<<<8, 256, 0, stream>>>(W2, wf2);

    const int agg_grid = N_NODES / 4;

    // --- layer 1 ---
    {
        dim3 g1(2, (N_NODES + 127) / 128);   // 2 col-blocks x 782 row-blocks
        gemm1_mfma<<<g1, 256, 0, stream>>>(xh, xl, wf1h, wf1l, dinv, hs1);
    }
    agg256<<<agg_grid, 256, 0, stream>>>(hs1, offsets, esrc, dinv, b1, r1s);

    // --- layer 2 ---
    gemm2_mfma<<<(N_NODES + 255) / 256, 256, 0, stream>>>(r1s, wf2, h2);
    agg64b<<<agg_grid, 256, 0, stream>>>(h2, offsets, esrc, dinv, b2, out);
}

// Round 8
// 494.136 us; speedup vs baseline: 14.5525x; 1.0356x over previous
//
#include <hip/hip_runtime.h>
#include <hip/hip_bf16.h>

#define N_NODES 100000
#define N_EDGES 1600000
#define D_FEAT 256
#define HIDDEN 256
#define N_CLASSES 64

#define NBKT 391                // buckets of 256 nodes: 99999>>8 = 390
#define TILE 4096               // edges per bin_scatter block
#define CAP  8192               // bucket_fill LDS staging (mean 4093, sigma 64)

typedef __attribute__((ext_vector_type(8))) short bf16x8;
typedef __attribute__((ext_vector_type(4))) float f32x4;

__device__ inline float b2f(ushort u) {
    unsigned v = ((unsigned)u) << 16;
    float f; __builtin_memcpy(&f, &v, 4); return f;
}
__device__ inline ushort f2b(float f) {   // RNE
    unsigned u; __builtin_memcpy(&u, &f, 4);
    unsigned r = (u + 0x7fffu + ((u >> 16) & 1u)) >> 16;
    return (ushort)r;
}

// ---------------- CSR build: bucketed two-phase ----------------
__global__ __launch_bounds__(256)
void zero_bcnt(int* bcnt) {
    int i = blockIdx.x * 256 + threadIdx.x;
    if (i < NBKT) bcnt[i] = 0;
}

__global__ __launch_bounds__(256)
void bin_count(const int* __restrict__ cols, int* bcnt, int nE) {
    __shared__ int h[NBKT];
    int t = threadIdx.x;
    for (int i = t; i < NBKT; i += 256) h[i] = 0;
    __syncthreads();
    for (long e = (long)blockIdx.x * 256 + t; e < nE; e += (long)gridDim.x * 256)
        atomicAdd(&h[cols[e] >> 8], 1);
    __syncthreads();
    for (int i = t; i < NBKT; i += 256)
        if (h[i]) atomicAdd(&bcnt[i], h[i]);
}

__global__ __launch_bounds__(256)
void bucket_scan(const int* __restrict__ bcnt, int* __restrict__ bbase,
                 int* __restrict__ bcur, int* __restrict__ offsets) {
    __shared__ int sd[256];
    int t = threadIdx.x;
    int i0 = 2 * t, i1 = 2 * t + 1;
    int a = (i0 < NBKT) ? bcnt[i0] : 0;
    int b = (i1 < NBKT) ? bcnt[i1] : 0;
    int s = a + b;
    sd[t] = s; __syncthreads();
    #pragma unroll
    for (int off = 1; off < 256; off <<= 1) {
        int v = (t >= off) ? sd[t - off] : 0;
        __syncthreads();
        sd[t] += v;
        __syncthreads();
    }
    int ex = sd[t] - s;
    if (i0 <= NBKT) bbase[i0] = ex;
    if (i0 < NBKT)  bcur[i0] = ex;
    if (i1 <= NBKT) bbase[i1] = ex + a;
    if (i1 < NBKT)  bcur[i1] = ex + a;
    if (t == 0) offsets[N_NODES] = N_EDGES;
}

// tile -> LDS sort by bucket -> batched reservation -> packed contiguous writes
__global__ __launch_bounds__(256)
void bin_scatter(const int* __restrict__ rows, const int* __restrict__ cols,
                 int* bcur, unsigned* __restrict__ bins, int nE)
{
    __shared__ unsigned recs[TILE];
    __shared__ ushort bos[TILE];
    __shared__ int hist[NBKT], excl[NBKT], cursor[NBKT], gbase[NBKT];
    __shared__ int sd[256];
    int t = threadIdx.x;
    long e0 = (long)blockIdx.x * TILE;
    int cnt = (int)min((long)TILE, (long)nE - e0);
    for (int i = t; i < NBKT; i += 256) hist[i] = 0;
    __syncthreads();
    int myrow[TILE / 256], mycol[TILE / 256];
    #pragma unroll
    for (int k = 0; k < TILE / 256; ++k) {
        int i = k * 256 + t;
        if (i < cnt) {
            myrow[k] = rows[e0 + i];
            mycol[k] = cols[e0 + i];
            atomicAdd(&hist[mycol[k] >> 8], 1);
        }
    }
    __syncthreads();
    {
        int i0 = 2 * t, i1 = 2 * t + 1;
        int a = (i0 < NBKT) ? hist[i0] : 0;
        int b = (i1 < NBKT) ? hist[i1] : 0;
        int s = a + b;
        sd[t] = s; __syncthreads();
        #pragma unroll
        for (int off = 1; off < 256; off <<= 1) {
            int v = (t >= off) ? sd[t - off] : 0;
            __syncthreads();
            sd[t] += v;
            __syncthreads();
        }
        int ex = sd[t] - s;
        if (i0 < NBKT) { excl[i0] = ex;     cursor[i0] = ex; }
        if (i1 < NBKT) { excl[i1] = ex + a; cursor[i1] = ex + a; }
    }
    __syncthreads();
    #pragma unroll
    for (int k = 0; k < TILE / 256; ++k) {
        int i = k * 256 + t;
        if (i < cnt) {
            int b = mycol[k] >> 8;
            int s = atomicAdd(&cursor[b], 1);
            recs[s] = ((unsigned)(mycol[k] & 255) << 24) | (unsigned)myrow[k];
            bos[s] = (ushort)b;
        }
    }
    __syncthreads();
    for (int i = t; i < NBKT; i += 256)
        if (hist[i] > 0) gbase[i] = atomicAdd(&bcur[i], hist[i]);
    __syncthreads();
    for (int i = t; i < cnt; i += 256) {
        int b = bos[i];
        bins[gbase[b] + (i - excl[b])] = recs[i];
    }
}

// one block per bucket: degrees -> dinv/offsets; LDS-staged coalesced esrc
__global__ __launch_bounds__(256)
void bucket_fill(const unsigned* __restrict__ bins, const int* __restrict__ bbase,
                 int* __restrict__ offsets, float* __restrict__ dinv,
                 int* __restrict__ esrc)
{
    int b = blockIdx.x, t = threadIdx.x;
    int s0 = bbase[b], s1 = bbase[b + 1];
    int len = s1 - s0;
    __shared__ int cnt[256];
    __shared__ int sd[256];
    __shared__ int cur[256];
    __shared__ int stage[CAP];
    cnt[t] = 0;
    __syncthreads();
    for (int i = t; i < len; i += 256) atomicAdd(&cnt[bins[s0 + i] >> 24], 1);
    __syncthreads();
    int c = cnt[t];
    sd[t] = c; __syncthreads();
    #pragma unroll
    for (int off = 1; off < 256; off <<= 1) {
        int v = (t >= off) ? sd[t - off] : 0;
        __syncthreads();
        sd[t] += v;
        __syncthreads();
    }
    int ex = sd[t] - c;
    cur[t] = ex;
    int node = b * 256 + t;
    if (node < N_NODES) {
        offsets[node] = s0 + ex;
        dinv[node] = rsqrtf(1.0f + (float)c);
    }
    __syncthreads();
    if (len <= CAP) {
        for (int i = t; i < len; i += 256) {
            unsigned r = bins[s0 + i];
            int p = atomicAdd(&cur[r >> 24], 1);
            stage[p] = (int)(r & 0xFFFFFFu);
        }
        __syncthreads();
        for (int i = t; i < len; i += 256) esrc[s0 + i] = stage[i];
    } else {   // statistically unreachable fallback (correctness guard)
        for (int i = t; i < len; i += 256) {
            unsigned r = bins[s0 + i];
            int p = atomicAdd(&cur[r >> 24], 1);
            esrc[s0 + p] = (int)(r & 0xFFFFFFu);
        }
    }
}

// ---------------- W1 (hi/lo) + W2 -> fragment-ordered bf16, one launch ------
__global__ __launch_bounds__(256)
void fragw(const float* __restrict__ W1, ushort* __restrict__ wfh,
           ushort* __restrict__ wfl,
           const float* __restrict__ W2, ushort* __restrict__ wf2) {
    int t = blockIdx.x * 256 + threadIdx.x;      // 10240 total
    int lane = t & 63;
    int m = lane & 15, quad = lane >> 4;
    if (t < 8192) {                               // W1: 8 ks x 16 nb x 64 lanes
        int ks = t >> 10, nb = (t >> 6) & 15;
        ushort h8[8], l8[8];
        #pragma unroll
        for (int j = 0; j < 8; ++j) {
            int k = ks * 32 + quad * 8 + j;
            float w = W1[k * HIDDEN + nb * 16 + m];
            h8[j] = f2b(w);
            l8[j] = f2b(w - b2f(h8[j]));
        }
        long off = ((long)(ks * 16 + nb) * 64 + lane) * 8;
        *(ushort4*)&wfh[off]     = make_ushort4(h8[0], h8[1], h8[2], h8[3]);
        *(ushort4*)&wfh[off + 4] = make_ushort4(h8[4], h8[5], h8[6], h8[7]);
        *(ushort4*)&wfl[off]     = make_ushort4(l8[0], l8[1], l8[2], l8[3]);
        *(ushort4*)&wfl[off + 4] = make_ushort4(l8[4], l8[5], l8[6], l8[7]);
    } else {                                      // W2: 8 ks x 4 nb x 64 lanes
        int u = t - 8192;
        int ks = u >> 8, nb = (u >> 6) & 3;
        ushort h8[8];
        #pragma unroll
        for (int j = 0; j < 8; ++j) {
            int k = ks * 32 + quad * 8 + j;
            h8[j] = f2b(W2[k * N_CLASSES + nb * 16 + m]);
        }
        long off = ((long)(ks * 4 + nb) * 64 + lane) * 8;
        *(ushort4*)&wf2[off]     = make_ushort4(h8[0], h8[1], h8[2], h8[3]);
        *(ushort4*)&wf2[off + 4] = make_ushort4(h8[4], h8[5], h8[6], h8[7]);
    }
}

// ---------------- GEMM1: hs = dinv[row] * (x @ W1), fused split, 3-product --
// wave = 64 rows x 64 cols, block = 2x2 waves = 128x128.
// x read directly as fp32; hi = truncate (lo catches remainder exactly).
__global__ __launch_bounds__(256)
void gemm1_mfma(const float* __restrict__ x,
                const ushort* __restrict__ wfh, const ushort* __restrict__ wfl,
                const float* __restrict__ dinv, ushort* __restrict__ hs)
{
    int tid = threadIdx.x;
    int lane = tid & 63;
    int wm = (tid >> 6) & 1;
    int wn = tid >> 7;
    int row0 = blockIdx.y * 128 + wm * 64;
    int nb0 = blockIdx.x * 8 + wn * 4;
    int m = lane & 15, quad = lane >> 4;

    f32x4 acc[4][4];
    #pragma unroll
    for (int i = 0; i < 4; ++i)
        #pragma unroll
        for (int j = 0; j < 4; ++j) acc[i][j] = (f32x4){0.f, 0.f, 0.f, 0.f};

    for (int ks = 0; ks < 8; ++ks) {
        bf16x8 ah[4], al[4];
        #pragma unroll
        for (int mf = 0; mf < 4; ++mf) {
            int rr = row0 + mf * 16 + m;
            rr = (rr < N_NODES) ? rr : (N_NODES - 1);   // clamp: x is exact-size
            const float* p = x + (long)rr * D_FEAT + ks * 32 + quad * 8;
            float4 v0 = *(const float4*)p;
            float4 v1 = *(const float4*)(p + 4);
            float vv[8] = {v0.x, v0.y, v0.z, v0.w, v1.x, v1.y, v1.z, v1.w};
            #pragma unroll
            for (int j = 0; j < 8; ++j) {
                unsigned u; __builtin_memcpy(&u, &vv[j], 4);
                ushort hh = (ushort)(u >> 16);           // truncate hi
                float hv = b2f(hh);
                ushort ll = f2b(vv[j] - hv);             // exact remainder, RNE
                ah[mf][j] = (short)hh;
                al[mf][j] = (short)ll;
            }
        }
        #pragma unroll
        for (int nbl = 0; nbl < 4; ++nbl) {
            long boff = ((long)(ks * 16 + nb0 + nbl) * 64 + lane) * 8;
            bf16x8 bh = *(const bf16x8*)(wfh + boff);
            bf16x8 bl = *(const bf16x8*)(wfl + boff);
            #pragma unroll
            for (int mf = 0; mf < 4; ++mf) {
                acc[mf][nbl] = __builtin_amdgcn_mfma_f32_16x16x32_bf16(ah[mf], bh, acc[mf][nbl], 0, 0, 0);
                acc[mf][nbl] = __builtin_amdgcn_mfma_f32_16x16x32_bf16(ah[mf], bl, acc[mf][nbl], 0, 0, 0);
                acc[mf][nbl] = __builtin_amdgcn_mfma_f32_16x16x32_bf16(al[mf], bh, acc[mf][nbl], 0, 0, 0);
            }
        }
    }

    #pragma unroll
    for (int mf = 0; mf < 4; ++mf)
        #pragma unroll
        for (int reg = 0; reg < 4; ++reg) {
            int row = row0 + mf * 16 + quad * 4 + reg;
            if (row < N_NODES) {
                float dv = dinv[row];
                #pragma unroll
                for (int nbl = 0; nbl < 4; ++nbl)
                    hs[(long)row * HIDDEN + (nb0 + nbl) * 16 + m] = f2b(acc[mf][nbl][reg] * dv);
            }
        }
}

// ---------------- GEMM2: h2 = r1s @ W2 (bf16 single) ----------------
__global__ __launch_bounds__(256)
void gemm2_mfma(const ushort* __restrict__ r1s, const ushort* __restrict__ wf,
                ushort* __restrict__ h2)
{
    int tid = threadIdx.x;
    int wv = tid >> 6, lane = tid & 63;
    int row0 = blockIdx.x * 256 + wv * 64;
    int m = lane & 15, quad = lane >> 4;

    f32x4 acc[4][4];
    #pragma unroll
    for (int i = 0; i < 4; ++i)
        #pragma unroll
        for (int j = 0; j < 4; ++j) acc[i][j] = (f32x4){0.f, 0.f, 0.f, 0.f};

    for (int ks = 0; ks < 8; ++ks) {
        bf16x8 a[4];
        #pragma unroll
        for (int mf = 0; mf < 4; ++mf) {
            long r = (long)(row0 + mf * 16 + m);
            a[mf] = *(const bf16x8*)(r1s + r * HIDDEN + ks * 32 + quad * 8);
        }
        #pragma unroll
        for (int nb = 0; nb < 4; ++nb) {
            bf16x8 b = *(const bf16x8*)(wf + ((long)(ks * 4 + nb) * 64 + lane) * 8);
            #pragma unroll
            for (int mf = 0; mf < 4; ++mf)
                acc[mf][nb] = __builtin_amdgcn_mfma_f32_16x16x32_bf16(a[mf], b, acc[mf][nb], 0, 0, 0);
        }
    }

    #pragma unroll
    for (int mf = 0; mf < 4; ++mf)
        #pragma unroll
        for (int reg = 0; reg < 4; ++reg) {
            int row = row0 + mf * 16 + quad * 4 + reg;
            if (row < N_NODES) {
                #pragma unroll
                for (int nb = 0; nb < 4; ++nb)
                    h2[(long)row * N_CLASSES + nb * 16 + m] = f2b(acc[mf][nb][reg]);
            }
        }
}

// ---------------- aggregate 256 feats bf16, unroll 8 ----------------
__global__ __launch_bounds__(256)
void agg256(const ushort* __restrict__ src, const int* __restrict__ offsets,
            const int* __restrict__ esrc, const float* __restrict__ dinv,
            const float* __restrict__ b1, ushort* __restrict__ dst)
{
    int wave = threadIdx.x >> 6, lane = threadIdx.x & 63;
    int v = blockIdx.x * 4 + wave;
    int c = lane << 2;
    ushort4 s = *(const ushort4*)&src[(long)v * 256 + c];
    float a0 = b2f(s.x), a1 = b2f(s.y), a2 = b2f(s.z), a3 = b2f(s.w);
    int e = offsets[v], end = offsets[v + 1];
    for (; e + 8 <= end; e += 8) {
        ushort4 u[8];
        #pragma unroll
        for (int j = 0; j < 8; ++j)
            u[j] = *(const ushort4*)&src[(long)esrc[e + j] * 256 + c];
        #pragma unroll
        for (int j = 0; j < 8; ++j) {
            a0 += b2f(u[j].x); a1 += b2f(u[j].y);
            a2 += b2f(u[j].z); a3 += b2f(u[j].w);
        }
    }
    for (; e < end; ++e) {
        ushort4 u = *(const ushort4*)&src[(long)esrc[e] * 256 + c];
        a0 += b2f(u.x); a1 += b2f(u.y); a2 += b2f(u.z); a3 += b2f(u.w);
    }
    float dv = dinv[v];
    float4 bb = *(const float4*)&b1[c];
    float r0 = dv * fmaxf(fmaf(dv, a0, bb.x), 0.f);
    float r1 = dv * fmaxf(fmaf(dv, a1, bb.y), 0.f);
    float r2 = dv * fmaxf(fmaf(dv, a2, bb.z), 0.f);
    float r3 = dv * fmaxf(fmaf(dv, a3, bb.w), 0.f);
    *(ushort4*)&dst[(long)v * 256 + c] = make_ushort4(f2b(r0), f2b(r1), f2b(r2), f2b(r3));
}

// ---------------- aggregate 64 feats bf16 -> fp32 out, unroll 8 -------------
__global__ __launch_bounds__(256)
void agg64b(const ushort* __restrict__ src, const int* __restrict__ offsets,
            const int* __restrict__ esrc, const float* __restrict__ dinv,
            const float* __restrict__ b2, float* __restrict__ out)
{
    int wave = threadIdx.x >> 6, lane = threadIdx.x & 63;
    int v = blockIdx.x * 4 + wave;
    float acc = b2f(src[(long)v * 64 + lane]);
    int e = offsets[v], end = offsets[v + 1];
    for (; e + 8 <= end; e += 8) {
        float a[8];
        #pragma unroll
        for (int j = 0; j < 8; ++j)
            a[j] = b2f(src[(long)esrc[e + j] * 64 + lane]);
        acc += ((a[0] + a[1]) + (a[2] + a[3])) + ((a[4] + a[5]) + (a[6] + a[7]));
    }
    for (; e < end; ++e) acc += b2f(src[(long)esrc[e] * 64 + lane]);
    out[(long)v * 64 + lane] = fmaf(dinv[v], acc, b2[lane]);
}

// ---------------- workspace layout (bytes, 16-aligned) ----------------
#define WS_DINV   0UL            // 400,000
#define WS_OFFS   524288UL       // 400,004
#define WS_BCNT   1048576UL      // 391*4
#define WS_BBASE  1052672UL      // 392*4
#define WS_BCUR   1056768UL      // 391*4
#define WS_ESRC   1064960UL      // 6,400,000
#define WS_BINS   7602176UL      // 6,400,000
#define WS_H2     20447232UL     // 100032*64*2  (only 64 wide needed)
#define WS_R1S    71663616UL     // 100032*256*2 = 51,216,384
#define WS_WF1H   122880000UL    // 131,072
#define WS_WF1L   123011072UL    // 131,072
#define WS_WF2    123142144UL    // 32,768
#define WS_HS1    123174912UL    // 51,216,384 -> end 174,391,296

extern "C" void kernel_launch(void* const* d_in, const int* in_sizes, int n_in,
                              void* d_out, int out_size, void* d_ws, size_t ws_size,
                              hipStream_t stream)
{
    const float* x  = (const float*)d_in[0];
    const int*   ei = (const int*)d_in[1];
    const float* W1 = (const float*)d_in[2];
    const float* b1 = (const float*)d_in[3];
    const float* W2 = (const float*)d_in[4];
    const float* b2 = (const float*)d_in[5];
    float* out = (float*)d_out;

    const int* rows = ei;            // sources
    const int* cols = ei + N_EDGES;  // targets

    char* ws = (char*)d_ws;
    float*    dinv    = (float*)(ws + WS_DINV);
    int*      offsets = (int*)(ws + WS_OFFS);
    int*      bcnt    = (int*)(ws + WS_BCNT);
    int*      bbase   = (int*)(ws + WS_BBASE);
    int*      bcur    = (int*)(ws + WS_BCUR);
    int*      esrc    = (int*)(ws + WS_ESRC);
    unsigned* bins    = (unsigned*)(ws + WS_BINS);
    ushort*   h2      = (ushort*)(ws + WS_H2);
    ushort*   r1s     = (ushort*)(ws + WS_R1S);
    ushort*   wf1h    = (ushort*)(ws + WS_WF1H);
    ushort*   wf1l    = (ushort*)(ws + WS_WF1L);
    ushort*   wf2     = (ushort*)(ws + WS_WF2);
    ushort*   hs1     = (ushort*)(ws + WS_HS1);

    // --- CSR build (bucketed) ---
    zero_bcnt<<<2, 256, 0, stream>>>(bcnt);
    bin_count<<<512, 256, 0, stream>>>(cols, bcnt, N_EDGES);
    bucket_scan<<<1, 256, 0, stream>>>(bcnt, bbase, bcur, offsets);
    bin_scatter<<<(N_EDGES + TILE - 1) / TILE, 256, 0, stream>>>(rows, cols, bcur, bins, N_EDGES);
    bucket_fill<<<NBKT, 256, 0, stream>>>(bins, bbase, offsets, dinv, esrc);

    // --- weight fragment prep (one launch) ---
    fragw<<<40, 256, 0, stream>>>(W1, wf1h, wf1l, W2, wf2);

    const int agg_grid = N_NODES / 4;

    // --- layer 1 ---
    {
        dim3 g1(2, (N_NODES + 127) / 128);
        gemm1_mfma<<<g1, 256, 0, stream>>>(x, wf1h, wf1l, dinv, hs1);
    }
    agg256<<<agg_grid, 256, 0, stream>>>(hs1, offsets, esrc, dinv, b1, r1s);

    // --- layer 2 ---
    gemm2_mfma<<<(N_NODES + 255) / 256, 256, 0, stream>>>(r1s, wf2, h2);
    agg64b<<<agg_grid, 256, 0, stream>>>(h2, offsets, esrc, dinv, b2, out);
}